// Round 5
// baseline (356.293 us; speedup 1.0000x reference)
//
#include <hip/hip_runtime.h>
#include <hip/hip_bf16.h>

// Problem constants
constexpr int kD  = 768;
constexpr int kH  = 12;
constexpr int kDH = 64;
constexpr int kS  = 1500;
constexpr int kSP = 1504;        // S padded to multiple of 32 (47*32)
constexpr int kB  = 8;
constexpr int kM  = kB * kS;     // 12000 rows for the projections
constexpr float kScale = 0.125f;
constexpr int kPSTR = 72;        // P row stride (elems): 144B -> b64/b128 aligned

typedef __bf16 bf16;
typedef __bf16 bf16x4 __attribute__((ext_vector_type(4)));
typedef __bf16 bf16x8 __attribute__((ext_vector_type(8)));
typedef float  floatx4 __attribute__((ext_vector_type(4)));

// ---------------------------------------------------------------------------
// Dtype probe (round-1 NaN proved inputs are f32; cheap guard retained).
// ---------------------------------------------------------------------------
__global__ __launch_bounds__(256) void detect_kernel(const void* __restrict__ xraw,
                                                     int* __restrict__ flag) {
    __shared__ int bad;
    if (threadIdx.x == 0) bad = 0;
    __syncthreads();
    const bf16* xb = (const bf16*)xraw;
    int c = 0;
    for (int k = 0; k < 16; k++) {
        int idx = 2 * (threadIdx.x + 256 * k);
        float v = fabsf((float)xb[idx]);
        if (!(v == 0.0f || (v > 1e-20f && v < 1e6f))) c++;
    }
    atomicAdd(&bad, c);
    __syncthreads();
    if (threadIdx.x == 0) *flag = (bad > 8) ? 1 : 0;
}

__global__ __launch_bounds__(256) void cvt_bf16_kernel(const void* __restrict__ src,
                                                       bf16* __restrict__ dst, int n,
                                                       const int* __restrict__ flag) {
    int i = blockIdx.x * 256 + threadIdx.x;
    if (i < n) {
        if (*flag)
            dst[i] = (bf16)((const float*)src)[i];
        else
            dst[i] = ((const bf16*)src)[i];
    }
}

__global__ __launch_bounds__(256) void cvt_f32_kernel(const void* __restrict__ src,
                                                      float* __restrict__ dst, int n,
                                                      const int* __restrict__ flag) {
    int i = blockIdx.x * 256 + threadIdx.x;
    if (i < n) {
        if (*flag)
            dst[i] = ((const float*)src)[i];
        else
            dst[i] = (float)((const bf16*)src)[i];
    }
}

// ---------------------------------------------------------------------------
// Zero the S-padding rows of q/k and padding cols of v^T.
// ---------------------------------------------------------------------------
__global__ __launch_bounds__(256) void zeropad_kernel(bf16* __restrict__ q_ws,
                                                      bf16* __restrict__ k_ws,
                                                      bf16* __restrict__ vt_ws) {
    int t = blockIdx.x * 256 + threadIdx.x;          // 96 bh * 4 s * 64 dh = 24576
    if (t < kB * kH * (kSP - kS) * kDH) {
        int bh  = t >> 8;
        int rem = t & 255;
        int s   = kS + (rem >> 6);
        int dh  = rem & 63;
        size_t qi = ((size_t)bh * kSP + s) * kDH + dh;
        q_ws[qi] = (bf16)0.f;
        k_ws[qi] = (bf16)0.f;
        size_t vi = ((size_t)bh * kDH + dh) * kSP + s;
        vt_ws[vi] = (bf16)0.f;
    }
}

// ---------------------------------------------------------------------------
// GEMM core v2: 128x128 tile, BK=32, 4 waves, 4x4 acc/wave, but now
// 2-PHASE DOUBLE-BUFFERED: STAGE(k+1) issued BEFORE compute(k), single
// vmcnt(0)+raw-s_barrier AFTER the MFMAs -> global-load latency hides
// under 8 ds_read_b128 + 16 MFMA instead of being fully exposed.
// (R4 counters: MfmaUtil 13.6%, VALU 15.5%, HBM 18% -> latency-exposed;
//  old structure drained vmcnt(0) immediately after issuing the loads.)
// ---------------------------------------------------------------------------
__device__ __forceinline__ void async_copy16(const bf16* g, bf16* l) {
    __builtin_amdgcn_global_load_lds(
        (const __attribute__((address_space(1))) void*)g,
        (__attribute__((address_space(3))) void*)l,
        16, 0, 0);
}

__device__ __forceinline__ void gemm128_db(const bf16* __restrict__ X,
                                           const bf16* __restrict__ W,
                                           int m0, int n0,
                                           bf16* Asm, bf16* Bsm,   // [2][4096] each
                                           floatx4 acc[4][4]) {
    const int tid  = threadIdx.x;
    const int lane = tid & 63;
    const int w    = tid >> 6;
    const int srow = (w << 4) + (lane >> 2);
    const int scol = (lane & 3) << 3;
    const int lrow = lane & 15;
    const int lq   = lane >> 4;
    const int wm   = (w >> 1) << 6;
    const int wn   = (w & 1) << 6;

    const bf16* gA = X + (size_t)(m0 + srow) * kD + scol;
    const bf16* gB = W + (size_t)(n0 + srow) * kD + scol;
    const int wof = w << 9;      // wave-uniform LDS base; HW adds lane*16B

    // prologue: stage K-step 0 into buffer 0
    async_copy16(gA, Asm + wof);
    async_copy16(gA + (size_t)64 * kD, Asm + wof + 2048);
    async_copy16(gB, Bsm + wof);
    async_copy16(gB + (size_t)64 * kD, Bsm + wof + 2048);
    asm volatile("s_waitcnt vmcnt(0)" ::: "memory");
    __builtin_amdgcn_s_barrier();

    for (int ks = 0; ks < kD / 32; ks++) {
        const int cur = ks & 1;
        if (ks + 1 < kD / 32) {                 // issue next-tile loads FIRST
            const int nb = (cur ^ 1) << 12;
            const int k0 = (ks + 1) * 32;
            async_copy16(gA + k0, Asm + nb + wof);
            async_copy16(gA + (size_t)64 * kD + k0, Asm + nb + wof + 2048);
            async_copy16(gB + k0, Bsm + nb + wof);
            async_copy16(gB + (size_t)64 * kD + k0, Bsm + nb + wof + 2048);
        }
        const bf16* A = Asm + (cur << 12);
        const bf16* B = Bsm + (cur << 12);
        bf16x8 af[4], bfr[4];
#pragma unroll
        for (int i = 0; i < 4; i++)
            af[i] = *(const bf16x8*)(A + ((wm + i * 16 + lrow) << 5) + (lq << 3));
#pragma unroll
        for (int j = 0; j < 4; j++)
            bfr[j] = *(const bf16x8*)(B + ((wn + j * 16 + lrow) << 5) + (lq << 3));
#pragma unroll
        for (int i = 0; i < 4; i++)
#pragma unroll
            for (int j = 0; j < 4; j++)
                acc[i][j] = __builtin_amdgcn_mfma_f32_16x16x32_bf16(
                    af[i], bfr[j], acc[i][j], 0, 0, 0);
        // drain the prefetch (issued ~compute-length ago) + barrier:
        // buf[cur] reads are complete (MFMA consumed them), so buf[cur]
        // may be overwritten next iteration.
        asm volatile("s_waitcnt vmcnt(0)" ::: "memory");
        __builtin_amdgcn_s_barrier();
    }
}

// Fused QKV projection. 1D grid of 1696 with XCD-pinned work remap:
// wk = (lin&7)*212 + lin>>3 puts all 18 (mat,n0)-blocks of one X-slab on
// ONE XCD -> X-tile fetched ~once per slab into that XCD's L2 (R4 FETCH
// was 102 MB vs 22 MB ideal from cross-XCD X re-reads). 4 dummy blocks
// (wk>=1692) return before any barrier.
__global__ __launch_bounds__(256) void qkv_kernel(const bf16* __restrict__ X,
                                                  const bf16* __restrict__ Wq,
                                                  const bf16* __restrict__ Wk,
                                                  const bf16* __restrict__ Wv,
                                                  const float* __restrict__ bq,
                                                  const float* __restrict__ bv,
                                                  bf16* __restrict__ q_ws,
                                                  bf16* __restrict__ k_ws,
                                                  bf16* __restrict__ vt_ws) {
    __shared__ bf16 Asm[2 * 4096];
    __shared__ bf16 Bsm[2 * 4096];

    const int lin = blockIdx.x;
    const int wk  = (lin & 7) * 212 + (lin >> 3);
    if (wk >= 94 * 18) return;
    const int bx  = wk / 18;
    const int r   = wk - bx * 18;
    const int m0  = bx << 7;
    const int mat = r / 6;
    const int n0  = (r % 6) << 7;
    const bf16* W = (mat == 0) ? Wq : (mat == 1) ? Wk : Wv;

    floatx4 acc[4][4] = {};
    gemm128_db(X, W, m0, n0, Asm, Bsm, acc);

    const int tid  = threadIdx.x;
    const int lane = tid & 63;
    const int w    = tid >> 6;
    const int lrow = lane & 15;
    const int lq   = lane >> 4;
    const int wm   = (w >> 1) << 6;
    const int wn   = (w & 1) << 6;

#pragma unroll
    for (int i = 0; i < 4; i++) {
#pragma unroll
        for (int j = 0; j < 4; j++) {
            const int n  = n0 + wn + j * 16 + lrow;
            const int hh = n >> 6, dh = n & 63;
            const float bval = (mat == 0) ? bq[n] : (mat == 2) ? bv[n] : 0.f;
#pragma unroll
            for (int r2 = 0; r2 < 4; r2++) {
                const int m = m0 + wm + i * 16 + lq * 4 + r2;
                if (m >= kM) continue;
                float v = acc[i][j][r2];
                if (mat == 0)      v = (v + bval) * kScale;
                else if (mat == 2) v = v + bval;
                const int bb = m / kS, s = m - bb * kS;
                if (mat == 2)
                    vt_ws[(((size_t)(bb * kH + hh)) * kDH + dh) * kSP + s] = (bf16)v;
                else if (mat == 1)
                    k_ws[(((size_t)(bb * kH + hh)) * kSP + s) * kDH + dh] = (bf16)v;
                else
                    q_ws[(((size_t)(bb * kH + hh)) * kSP + s) * kDH + dh] = (bf16)v;
            }
        }
    }
}

__global__ __launch_bounds__(256) void out_kernel(const bf16* __restrict__ X,
                                                  const bf16* __restrict__ Wo,
                                                  const float* __restrict__ bo,
                                                  float* __restrict__ outf) {
    __shared__ bf16 Asm[2 * 4096];
    __shared__ bf16 Bsm[2 * 4096];

    const int m0 = blockIdx.x << 7;
    const int n0 = blockIdx.y << 7;

    floatx4 acc[4][4] = {};
    gemm128_db(X, Wo, m0, n0, Asm, Bsm, acc);

    const int tid  = threadIdx.x;
    const int lane = tid & 63;
    const int w    = tid >> 6;
    const int lrow = lane & 15;
    const int lq   = lane >> 4;
    const int wm   = (w >> 1) << 6;
    const int wn   = (w & 1) << 6;

#pragma unroll
    for (int i = 0; i < 4; i++) {
#pragma unroll
        for (int j = 0; j < 4; j++) {
            const int n = n0 + wn + j * 16 + lrow;
            const float bval = bo[n];
#pragma unroll
            for (int r = 0; r < 4; r++) {
                const int m = m0 + wm + i * 16 + lq * 4 + r;
                if (m >= kM) continue;
                outf[(size_t)m * kD + n] = acc[i][j][r] + bval;
            }
        }
    }
}

// ---------------------------------------------------------------------------
// Flash attention v7 (UNCHANGED this round): K/V staged in LDS via
// global_load_lds, double-buffered, shared by all 4 waves; XOR bank swizzle
// (linear LDS dest + inverse-swizzled global source + swizzled read).
// ---------------------------------------------------------------------------
__device__ __forceinline__ const bf16* lds_at(const bf16* sm, int row, int cb) {
    // row-major [64][128B] tile with XOR bank swizzle on the byte column
    return sm + row * 64 + ((cb ^ ((row & 7) << 4)) >> 1);
}

__device__ __forceinline__ void stage_k(const bf16* __restrict__ kbase, int s0,
                                        bf16* ksm, int w, int lane) {
#pragma unroll
    for (int i = 0; i < 2; i++) {
        const int sidx = i * 4 + w;
        const int row  = sidx * 8 + (lane >> 3);
        const int cb   = (lane & 7) << 4;
        const int scb  = cb ^ ((row & 7) << 4);
        int gr = s0 + row;
        if (gr >= kSP) gr = 1472;                    // tail clamp (finite data)
        async_copy16(kbase + (size_t)gr * kDH + (scb >> 1), ksm + sidx * 512);
    }
}

__device__ __forceinline__ void stage_v(const bf16* __restrict__ vbase, int s0,
                                        bf16* vsm, int w, int lane) {
#pragma unroll
    for (int i = 0; i < 2; i++) {
        const int sidx = i * 4 + w;
        const int row  = sidx * 8 + (lane >> 3);     // dh
        const int cb   = (lane & 7) << 4;
        const int scb  = cb ^ ((row & 7) << 4);
        int key = s0 + (scb >> 1);
        if (key >= kSP) key = 1472;                  // tail clamp (finite data)
        async_copy16(vbase + (size_t)row * kSP + key, vsm + sidx * 512);
    }
}

__device__ __forceinline__ void qk_mfma_lds(const bf16* ksm,
                                            const bf16x8 qf[2][2],
                                            floatx4 sc[2][4],
                                            int col, int quad) {
#pragma unroll
    for (int t = 0; t < 4; t++) {
        const int r = 16 * t + col;
        const bf16x8 kf0 = *(const bf16x8*)lds_at(ksm, r, quad * 16);
        const bf16x8 kf1 = *(const bf16x8*)lds_at(ksm, r, 64 + quad * 16);
        __builtin_amdgcn_s_setprio(1);
#pragma unroll
        for (int qt = 0; qt < 2; qt++) {
            floatx4 a = {0.f, 0.f, 0.f, 0.f};
            a = __builtin_amdgcn_mfma_f32_16x16x32_bf16(kf0, qf[qt][0], a, 0, 0, 0);
            a = __builtin_amdgcn_mfma_f32_16x16x32_bf16(kf1, qf[qt][1], a, 0, 0, 0);
            sc[qt][t] = a;
        }
        __builtin_amdgcn_s_setprio(0);
    }
}

template <bool MASK>
__device__ __forceinline__ void exp_store(const floatx4 sc[2][4],
                                          bf16* __restrict__ Pw,
                                          float lsum[2],
                                          int s0, int col, int quad) {
#pragma unroll
    for (int qt = 0; qt < 2; qt++)
#pragma unroll
        for (int t = 0; t < 4; t++) {
            bf16x4 pv;
#pragma unroll
            for (int r = 0; r < 4; r++) {
                float p;
                if (MASK && (s0 + 16 * t + quad * 4 + r >= kS))
                    p = 0.f;
                else
                    p = __expf(sc[qt][t][r]);
                lsum[qt] += p;
                pv[r] = (bf16)p;
            }
            *(bf16x4*)(Pw + (qt * 16 + col) * kPSTR + 16 * t + quad * 4) = pv;
        }
}

__device__ __forceinline__ void pv_lds(const bf16* vsm,
                                       const bf16* __restrict__ Pr,
                                       floatx4 Oacc[2][4],
                                       int col, int quad) {
    bf16x8 pa[2][2];
#pragma unroll
    for (int qt = 0; qt < 2; qt++)
#pragma unroll
        for (int kc = 0; kc < 2; kc++)
            pa[qt][kc] = *(const bf16x8*)(Pr + (qt * 16 + col) * kPSTR + kc * 32 + quad * 8);
#pragma unroll
    for (int n = 0; n < 4; n++) {
        const int row = n * 16 + col;                // dh row of V^T tile
#pragma unroll
        for (int kc = 0; kc < 2; kc++) {
            const bf16x8 vf = *(const bf16x8*)lds_at(vsm, row, kc * 64 + quad * 16);
            __builtin_amdgcn_s_setprio(1);
#pragma unroll
            for (int qt = 0; qt < 2; qt++)
                Oacc[qt][n] = __builtin_amdgcn_mfma_f32_16x16x32_bf16(
                    pa[qt][kc], vf, Oacc[qt][n], 0, 0, 0);
            __builtin_amdgcn_s_setprio(0);
        }
    }
}

__global__ __launch_bounds__(256, 2) void fattn_kernel(const bf16* __restrict__ q_ws,
                                                       const bf16* __restrict__ k_ws,
                                                       const bf16* __restrict__ vt_ws,
                                                       bf16* __restrict__ ctx) {
    __shared__ bf16 Ksm[2][64 * 64];       // 16 KB double-buffered K tile
    __shared__ bf16 Vsm[2][64 * 64];       // 16 KB double-buffered V^T tile
    __shared__ bf16 Pbuf[4][32 * kPSTR];   // 18 KB per-wave P slices -> 50 KB total

    const int idx = blockIdx.x;         // 0..1151; bh fastest -> idx%8 = bh%8 (XCD)
    const int bh  = idx % 96;
    const int qb  = idx / 96;           // 0..11, 128 Q rows per block
    const int b   = bh / kH;
    const int h   = bh - b * kH;
    const int tid  = threadIdx.x;
    const int w    = tid >> 6;
    const int lane = tid & 63;
    const int col  = lane & 15;         // q index within a 16-row tile
    const int quad = lane >> 4;
    const int q0   = qb * 128 + w * 32; // this wave's 32 Q rows (2 tiles)
    const bool active = (q0 < kS);      // wave-uniform; inactive waves still
                                        // stage + hit every barrier

    const bf16* qbase = q_ws  + (size_t)bh * kSP * kDH;
    const bf16* kbase = k_ws  + (size_t)bh * kSP * kDH;
    const bf16* vbase = vt_ws + (size_t)bh * kDH * kSP;

    bf16x8 qf[2][2] = {};
    if (active) {
#pragma unroll
        for (int qt = 0; qt < 2; qt++) {
            const bf16* qr = qbase + (size_t)(q0 + qt * 16 + col) * kDH + quad * 8;
            qf[qt][0] = *(const bf16x8*)(qr);
            qf[qt][1] = *(const bf16x8*)(qr + 32);
        }
    }

    float lsum[2] = {0.f, 0.f};
    floatx4 Oacc[2][4];
#pragma unroll
    for (int qt = 0; qt < 2; qt++)
#pragma unroll
        for (int n = 0; n < 4; n++) Oacc[qt][n] = (floatx4){0.f, 0.f, 0.f, 0.f};

    bf16* const P = &Pbuf[w][0];
    floatx4 sc[2][4];

    // prologue: stage chunk 0
    stage_k(kbase, 0, &Ksm[0][0], w, lane);
    stage_v(vbase, 0, &Vsm[0][0], w, lane);
    __syncthreads();

    int buf = 0;
    // chunks 0..22: stage next, compute current, one barrier per chunk
    for (int c = 0; c < 23; ++c) {
        stage_k(kbase, (c + 1) * 64, &Ksm[buf ^ 1][0], w, lane);
        stage_v(vbase, (c + 1) * 64, &Vsm[buf ^ 1][0], w, lane);
        if (active) {
            qk_mfma_lds(&Ksm[buf][0], qf, sc, col, quad);
            exp_store<false>(sc, P, lsum, c * 64, col, quad);
            pv_lds(&Vsm[buf][0], P, Oacc, col, quad);
        }
        __syncthreads();
        buf ^= 1;
    }
    // chunk 23 (keys 1472..1535; >=1500 masked to exact-zero P)
    if (active) {
        qk_mfma_lds(&Ksm[buf][0], qf, sc, col, quad);
        exp_store<true>(sc, P, lsum, 1472, col, quad);
        pv_lds(&Vsm[buf][0], P, Oacc, col, quad);

#pragma unroll
        for (int qt = 0; qt < 2; qt++) {
            float l = lsum[qt];
            l += __shfl_xor(l, 16);
            l += __shfl_xor(l, 32);
            const float rinv_col = 1.0f / l;         // for q = col of this tile
            float ri[4];
#pragma unroll
            for (int r = 0; r < 4; r++)
                ri[r] = __shfl(rinv_col, quad * 4 + r, 16);
#pragma unroll
            for (int n = 0; n < 4; n++)
#pragma unroll
                for (int r = 0; r < 4; r++) {
                    const int q = q0 + qt * 16 + quad * 4 + r;
                    if (q < kS)
                        ctx[((size_t)(b * kS + q)) * kD + h * kDH + n * 16 + col] =
                            (bf16)(Oacc[qt][n][r] * ri[r]);
                }
        }
    }
}

// ---------------------------------------------------------------------------
extern "C" void kernel_launch(void* const* d_in, const int* in_sizes, int n_in,
                              void* d_out, int out_size, void* d_ws, size_t ws_size,
                              hipStream_t stream) {
    float* out_f = (float*)d_out;   // reference output dtype is float32

    constexpr size_t nX = (size_t)kM * kD;
    constexpr size_t nW = (size_t)kD * kD;
    constexpr size_t per_qkv = (size_t)kB * kH * kSP * kDH;

    bf16* xb    = (bf16*)d_ws;
    bf16* Wqb   = xb + nX;
    bf16* Wkb   = Wqb + nW;
    bf16* Wvb   = Wkb + nW;
    bf16* Wob   = Wvb + nW;
    bf16* q_ws  = Wob + nW;
    bf16* k_ws  = q_ws + per_qkv;
    bf16* vt_ws = k_ws + per_qkv;
    float* bqf  = (float*)(vt_ws + per_qkv);
    float* bvf  = bqf + kD;
    float* bof  = bvf + kD;
    int*  flag  = (int*)(bof + kD);
    bf16* ctx   = xb;   // alias: xb last read by qkv_kernel, ctx written after

    // 1) dtype probe + input normalization to bf16 (biases to f32)
    detect_kernel<<<1, 256, 0, stream>>>(d_in[0], flag);
    cvt_bf16_kernel<<<(int)((nX + 255) / 256), 256, 0, stream>>>(d_in[0], xb,  (int)nX, flag);
    cvt_bf16_kernel<<<(int)((nW + 255) / 256), 256, 0, stream>>>(d_in[1], Wqb, (int)nW, flag);
    cvt_bf16_kernel<<<(int)((nW + 255) / 256), 256, 0, stream>>>(d_in[3], Wkb, (int)nW, flag);
    cvt_bf16_kernel<<<(int)((nW + 255) / 256), 256, 0, stream>>>(d_in[4], Wvb, (int)nW, flag);
    cvt_bf16_kernel<<<(int)((nW + 255) / 256), 256, 0, stream>>>(d_in[6], Wob, (int)nW, flag);
    cvt_f32_kernel<<<3, 256, 0, stream>>>(d_in[2], bqf, kD, flag);
    cvt_f32_kernel<<<3, 256, 0, stream>>>(d_in[5], bvf, kD, flag);
    cvt_f32_kernel<<<3, 256, 0, stream>>>(d_in[7], bof, kD, flag);

    // 2) fused QKV projection (+ padding): 1D grid 1696, XCD-pinned remap
    zeropad_kernel<<<96, 256, 0, stream>>>(q_ws, k_ws, vt_ws);
    qkv_kernel<<<dim3(1696), 256, 0, stream>>>(xb, Wqb, Wkb, Wvb, bqf, bvf,
                                               q_ws, k_ws, vt_ws);

    // 3) flash attention (1D grid: 12 q-blocks x 96 bh, bh fastest for XCD pin)
    fattn_kernel<<<dim3(12 * 96), 256, 0, stream>>>(q_ws, k_ws, vt_ws, ctx);

    // 4) output projection -> float32 d_out
    dim3 ogrid((kM + 127) / 128, kD / 128);   // 94 x 6
    out_kernel<<<ogrid, 256, 0, stream>>>(ctx, Wob, bof, out_f);
}

// Round 6
// 345.896 us; speedup vs baseline: 1.0301x; 1.0301x over previous
//
#include <hip/hip_runtime.h>
#include <hip/hip_bf16.h>

// Problem constants
constexpr int kD  = 768;
constexpr int kH  = 12;
constexpr int kDH = 64;
constexpr int kS  = 1500;
constexpr int kSP = 1504;        // S padded to multiple of 32 (47*32)
constexpr int kB  = 8;
constexpr int kM  = kB * kS;     // 12000 rows for the projections
constexpr float kScale = 0.125f;
constexpr int kPSTR = 72;        // P row stride (elems): 144B -> b64/b128 aligned
constexpr int kNK = kD / 32;     // 24 K-steps in the projections

typedef __bf16 bf16;
typedef __bf16 bf16x4 __attribute__((ext_vector_type(4)));
typedef __bf16 bf16x8 __attribute__((ext_vector_type(8)));
typedef float  floatx4 __attribute__((ext_vector_type(4)));

// ---------------------------------------------------------------------------
// Dtype probe (round-1 NaN proved inputs are f32; cheap guard retained).
// ---------------------------------------------------------------------------
__global__ __launch_bounds__(256) void detect_kernel(const void* __restrict__ xraw,
                                                     int* __restrict__ flag) {
    __shared__ int bad;
    if (threadIdx.x == 0) bad = 0;
    __syncthreads();
    const bf16* xb = (const bf16*)xraw;
    int c = 0;
    for (int k = 0; k < 16; k++) {
        int idx = 2 * (threadIdx.x + 256 * k);
        float v = fabsf((float)xb[idx]);
        if (!(v == 0.0f || (v > 1e-20f && v < 1e6f))) c++;
    }
    atomicAdd(&bad, c);
    __syncthreads();
    if (threadIdx.x == 0) *flag = (bad > 8) ? 1 : 0;
}

__global__ __launch_bounds__(256) void cvt_bf16_kernel(const void* __restrict__ src,
                                                       bf16* __restrict__ dst, int n,
                                                       const int* __restrict__ flag) {
    int i = blockIdx.x * 256 + threadIdx.x;
    if (i < n) {
        if (*flag)
            dst[i] = (bf16)((const float*)src)[i];
        else
            dst[i] = ((const bf16*)src)[i];
    }
}

__global__ __launch_bounds__(256) void cvt_f32_kernel(const void* __restrict__ src,
                                                      float* __restrict__ dst, int n,
                                                      const int* __restrict__ flag) {
    int i = blockIdx.x * 256 + threadIdx.x;
    if (i < n) {
        if (*flag)
            dst[i] = ((const float*)src)[i];
        else
            dst[i] = (float)((const bf16*)src)[i];
    }
}

// ---------------------------------------------------------------------------
// Zero the S-padding rows of q/k and padding cols of v^T.
// ---------------------------------------------------------------------------
__global__ __launch_bounds__(256) void zeropad_kernel(bf16* __restrict__ q_ws,
                                                      bf16* __restrict__ k_ws,
                                                      bf16* __restrict__ vt_ws) {
    int t = blockIdx.x * 256 + threadIdx.x;          // 96 bh * 4 s * 64 dh = 24576
    if (t < kB * kH * (kSP - kS) * kDH) {
        int bh  = t >> 8;
        int rem = t & 255;
        int s   = kS + (rem >> 6);
        int dh  = rem & 63;
        size_t qi = ((size_t)bh * kSP + s) * kDH + dh;
        q_ws[qi] = (bf16)0.f;
        k_ws[qi] = (bf16)0.f;
        size_t vi = ((size_t)bh * kDH + dh) * kSP + s;
        vt_ws[vi] = (bf16)0.f;
    }
}

// ---------------------------------------------------------------------------
// GEMM core v3: 128x128 tile, BK=32, 4 waves, 4x4 acc/wave.
// TRIPLE-BUFFERED, 2-DEEP PREFETCH, COUNTED vmcnt(4) (T4):
//   iter k: STAGE(k+2 -> buf[(k+2)%3]); COMPUTE(buf[k%3]);
//           s_waitcnt vmcnt(4)   <- waits only for stage(k+1), issued a FULL
//                                   iteration earlier; stage(k+2) stays in
//                                   flight across the barrier (never drain 0
//                                   in the main loop);
//           s_barrier; sched_barrier(0).
// R5 disproved drain-0 double-buffering: dur identical (125.7us) because the
// end-of-iter vmcnt(0) waited on loads issued the SAME iteration (compute
// ~300cy < load latency ~400-900cy). Fully unrolled so buffer indices and
// vmcnt immediates are compile-time.
// Race audit: reads of buf[k%3] complete before iter-k barrier (lgkmcnt
// before MFMA); its overwrite stage(k+3) issues after that barrier; buffers
// in flight distinct mod 3; per-wave vmcnt + barrier => cross-wave safe.
// ---------------------------------------------------------------------------
__device__ __forceinline__ void async_copy16(const bf16* g, bf16* l) {
    __builtin_amdgcn_global_load_lds(
        (const __attribute__((address_space(1))) void*)g,
        (__attribute__((address_space(3))) void*)l,
        16, 0, 0);
}

#define G_STAGE(KK, SB)                                                         \
    {                                                                           \
        const int k0_ = (KK) * 32;                                              \
        async_copy16(gA + k0_, Asm + (SB) * 4096 + wof);                        \
        async_copy16(gA + (size_t)64 * kD + k0_, Asm + (SB) * 4096 + wof + 2048); \
        async_copy16(gB + k0_, Bsm + (SB) * 4096 + wof);                        \
        async_copy16(gB + (size_t)64 * kD + k0_, Bsm + (SB) * 4096 + wof + 2048); \
    }

#define G_COMPUTE(CB)                                                           \
    {                                                                           \
        const bf16* A_ = Asm + (CB) * 4096;                                     \
        const bf16* B_ = Bsm + (CB) * 4096;                                     \
        bf16x8 af[4], bfr[4];                                                   \
        _Pragma("unroll") for (int i = 0; i < 4; i++)                           \
            af[i] = *(const bf16x8*)(A_ + ((wm + i * 16 + lrow) << 5) + (lq << 3)); \
        _Pragma("unroll") for (int j = 0; j < 4; j++)                           \
            bfr[j] = *(const bf16x8*)(B_ + ((wn + j * 16 + lrow) << 5) + (lq << 3)); \
        _Pragma("unroll") for (int i = 0; i < 4; i++)                           \
            _Pragma("unroll") for (int j = 0; j < 4; j++)                       \
                acc[i][j] = __builtin_amdgcn_mfma_f32_16x16x32_bf16(            \
                    af[i], bfr[j], acc[i][j], 0, 0, 0);                         \
    }

#define G_STEP(KK, CB, SB)                                                      \
    {                                                                           \
        if ((KK) + 2 < kNK) G_STAGE((KK) + 2, SB);                              \
        G_COMPUTE(CB);                                                          \
        if ((KK) + 1 < kNK) {                                                   \
            if ((KK) + 2 < kNK) {                                               \
                asm volatile("s_waitcnt vmcnt(4)" ::: "memory");                \
            } else {                                                            \
                asm volatile("s_waitcnt vmcnt(0)" ::: "memory");                \
            }                                                                   \
            __builtin_amdgcn_s_barrier();                                       \
            __builtin_amdgcn_sched_barrier(0);                                  \
        }                                                                       \
    }

__device__ __forceinline__ void gemm128_tb(const bf16* __restrict__ X,
                                           const bf16* __restrict__ W,
                                           int m0, int n0,
                                           bf16* Asm, bf16* Bsm,   // [3][4096] each
                                           floatx4 acc[4][4]) {
    const int tid  = threadIdx.x;
    const int lane = tid & 63;
    const int w    = tid >> 6;
    const int srow = (w << 4) + (lane >> 2);
    const int scol = (lane & 3) << 3;
    const int lrow = lane & 15;
    const int lq   = lane >> 4;
    const int wm   = (w >> 1) << 6;
    const int wn   = (w & 1) << 6;

    const bf16* gA = X + (size_t)(m0 + srow) * kD + scol;
    const bf16* gB = W + (size_t)(n0 + srow) * kD + scol;
    const int wof = w << 9;      // wave-uniform LDS base; HW adds lane*16B

    // prologue: stage K-steps 0,1 into buffers 0,1; wait only for step 0
    G_STAGE(0, 0);
    G_STAGE(1, 1);
    asm volatile("s_waitcnt vmcnt(4)" ::: "memory");
    __builtin_amdgcn_s_barrier();
    __builtin_amdgcn_sched_barrier(0);

#pragma unroll
    for (int ks = 0; ks < kNK; ks += 3) {
        G_STEP(ks,     0, 2);
        G_STEP(ks + 1, 1, 0);
        G_STEP(ks + 2, 2, 1);
    }
}

// Fused QKV projection. 1D grid of 1696 with XCD-pinned work remap:
// wk = (lin&7)*212 + lin>>3 puts all 18 (mat,n0)-blocks of one X-slab on
// ONE XCD (kept: R5 FETCH 102->53 MB). 4 dummy blocks return pre-barrier.
__global__ __launch_bounds__(256) void qkv_kernel(const bf16* __restrict__ X,
                                                  const bf16* __restrict__ Wq,
                                                  const bf16* __restrict__ Wk,
                                                  const bf16* __restrict__ Wv,
                                                  const float* __restrict__ bq,
                                                  const float* __restrict__ bv,
                                                  bf16* __restrict__ q_ws,
                                                  bf16* __restrict__ k_ws,
                                                  bf16* __restrict__ vt_ws) {
    __shared__ bf16 Asm[3 * 4096];
    __shared__ bf16 Bsm[3 * 4096];

    const int lin = blockIdx.x;
    const int wk  = (lin & 7) * 212 + (lin >> 3);
    if (wk >= 94 * 18) return;
    const int bx  = wk / 18;
    const int r   = wk - bx * 18;
    const int m0  = bx << 7;
    const int mat = r / 6;
    const int n0  = (r % 6) << 7;
    const bf16* W = (mat == 0) ? Wq : (mat == 1) ? Wk : Wv;

    floatx4 acc[4][4] = {};
    gemm128_tb(X, W, m0, n0, Asm, Bsm, acc);

    const int tid  = threadIdx.x;
    const int lane = tid & 63;
    const int w    = tid >> 6;
    const int lrow = lane & 15;
    const int lq   = lane >> 4;
    const int wm   = (w >> 1) << 6;
    const int wn   = (w & 1) << 6;

#pragma unroll
    for (int i = 0; i < 4; i++) {
#pragma unroll
        for (int j = 0; j < 4; j++) {
            const int n  = n0 + wn + j * 16 + lrow;
            const int hh = n >> 6, dh = n & 63;
            const float bval = (mat == 0) ? bq[n] : (mat == 2) ? bv[n] : 0.f;
#pragma unroll
            for (int r2 = 0; r2 < 4; r2++) {
                const int m = m0 + wm + i * 16 + lq * 4 + r2;
                if (m >= kM) continue;
                float v = acc[i][j][r2];
                if (mat == 0)      v = (v + bval) * kScale;
                else if (mat == 2) v = v + bval;
                const int bb = m / kS, s = m - bb * kS;
                if (mat == 2)
                    vt_ws[(((size_t)(bb * kH + hh)) * kDH + dh) * kSP + s] = (bf16)v;
                else if (mat == 1)
                    k_ws[(((size_t)(bb * kH + hh)) * kSP + s) * kDH + dh] = (bf16)v;
                else
                    q_ws[(((size_t)(bb * kH + hh)) * kSP + s) * kDH + dh] = (bf16)v;
            }
        }
    }
}

__global__ __launch_bounds__(256) void out_kernel(const bf16* __restrict__ X,
                                                  const bf16* __restrict__ Wo,
                                                  const float* __restrict__ bo,
                                                  float* __restrict__ outf) {
    __shared__ bf16 Asm[3 * 4096];
    __shared__ bf16 Bsm[3 * 4096];

    const int m0 = blockIdx.x << 7;
    const int n0 = blockIdx.y << 7;

    floatx4 acc[4][4] = {};
    gemm128_tb(X, Wo, m0, n0, Asm, Bsm, acc);

    const int tid  = threadIdx.x;
    const int lane = tid & 63;
    const int w    = tid >> 6;
    const int lrow = lane & 15;
    const int lq   = lane >> 4;
    const int wm   = (w >> 1) << 6;
    const int wn   = (w & 1) << 6;

#pragma unroll
    for (int i = 0; i < 4; i++) {
#pragma unroll
        for (int j = 0; j < 4; j++) {
            const int n = n0 + wn + j * 16 + lrow;
            const float bval = bo[n];
#pragma unroll
            for (int r = 0; r < 4; r++) {
                const int m = m0 + wm + i * 16 + lq * 4 + r;
                if (m >= kM) continue;
                outf[(size_t)m * kD + n] = acc[i][j][r] + bval;
            }
        }
    }
}

// ---------------------------------------------------------------------------
// Flash attention v7 (UNCHANGED this round): K/V staged in LDS via
// global_load_lds, double-buffered, shared by all 4 waves; XOR bank swizzle
// (linear LDS dest + inverse-swizzled global source + swizzled read).
// ---------------------------------------------------------------------------
__device__ __forceinline__ const bf16* lds_at(const bf16* sm, int row, int cb) {
    // row-major [64][128B] tile with XOR bank swizzle on the byte column
    return sm + row * 64 + ((cb ^ ((row & 7) << 4)) >> 1);
}

__device__ __forceinline__ void stage_k(const bf16* __restrict__ kbase, int s0,
                                        bf16* ksm, int w, int lane) {
#pragma unroll
    for (int i = 0; i < 2; i++) {
        const int sidx = i * 4 + w;
        const int row  = sidx * 8 + (lane >> 3);
        const int cb   = (lane & 7) << 4;
        const int scb  = cb ^ ((row & 7) << 4);
        int gr = s0 + row;
        if (gr >= kSP) gr = 1472;                    // tail clamp (finite data)
        async_copy16(kbase + (size_t)gr * kDH + (scb >> 1), ksm + sidx * 512);
    }
}

__device__ __forceinline__ void stage_v(const bf16* __restrict__ vbase, int s0,
                                        bf16* vsm, int w, int lane) {
#pragma unroll
    for (int i = 0; i < 2; i++) {
        const int sidx = i * 4 + w;
        const int row  = sidx * 8 + (lane >> 3);     // dh
        const int cb   = (lane & 7) << 4;
        const int scb  = cb ^ ((row & 7) << 4);
        int key = s0 + (scb >> 1);
        if (key >= kSP) key = 1472;                  // tail clamp (finite data)
        async_copy16(vbase + (size_t)row * kSP + key, vsm + sidx * 512);
    }
}

__device__ __forceinline__ void qk_mfma_lds(const bf16* ksm,
                                            const bf16x8 qf[2][2],
                                            floatx4 sc[2][4],
                                            int col, int quad) {
#pragma unroll
    for (int t = 0; t < 4; t++) {
        const int r = 16 * t + col;
        const bf16x8 kf0 = *(const bf16x8*)lds_at(ksm, r, quad * 16);
        const bf16x8 kf1 = *(const bf16x8*)lds_at(ksm, r, 64 + quad * 16);
        __builtin_amdgcn_s_setprio(1);
#pragma unroll
        for (int qt = 0; qt < 2; qt++) {
            floatx4 a = {0.f, 0.f, 0.f, 0.f};
            a = __builtin_amdgcn_mfma_f32_16x16x32_bf16(kf0, qf[qt][0], a, 0, 0, 0);
            a = __builtin_amdgcn_mfma_f32_16x16x32_bf16(kf1, qf[qt][1], a, 0, 0, 0);
            sc[qt][t] = a;
        }
        __builtin_amdgcn_s_setprio(0);
    }
}

template <bool MASK>
__device__ __forceinline__ void exp_store(const floatx4 sc[2][4],
                                          bf16* __restrict__ Pw,
                                          float lsum[2],
                                          int s0, int col, int quad) {
#pragma unroll
    for (int qt = 0; qt < 2; qt++)
#pragma unroll
        for (int t = 0; t < 4; t++) {
            bf16x4 pv;
#pragma unroll
            for (int r = 0; r < 4; r++) {
                float p;
                if (MASK && (s0 + 16 * t + quad * 4 + r >= kS))
                    p = 0.f;
                else
                    p = __expf(sc[qt][t][r]);
                lsum[qt] += p;
                pv[r] = (bf16)p;
            }
            *(bf16x4*)(Pw + (qt * 16 + col) * kPSTR + 16 * t + quad * 4) = pv;
        }
}

__device__ __forceinline__ void pv_lds(const bf16* vsm,
                                       const bf16* __restrict__ Pr,
                                       floatx4 Oacc[2][4],
                                       int col, int quad) {
    bf16x8 pa[2][2];
#pragma unroll
    for (int qt = 0; qt < 2; qt++)
#pragma unroll
        for (int kc = 0; kc < 2; kc++)
            pa[qt][kc] = *(const bf16x8*)(Pr + (qt * 16 + col) * kPSTR + kc * 32 + quad * 8);
#pragma unroll
    for (int n = 0; n < 4; n++) {
        const int row = n * 16 + col;                // dh row of V^T tile
#pragma unroll
        for (int kc = 0; kc < 2; kc++) {
            const bf16x8 vf = *(const bf16x8*)lds_at(vsm, row, kc * 64 + quad * 16);
            __builtin_amdgcn_s_setprio(1);
#pragma unroll
            for (int qt = 0; qt < 2; qt++)
                Oacc[qt][n] = __builtin_amdgcn_mfma_f32_16x16x32_bf16(
                    pa[qt][kc], vf, Oacc[qt][n], 0, 0, 0);
            __builtin_amdgcn_s_setprio(0);
        }
    }
}

__global__ __launch_bounds__(256, 2) void fattn_kernel(const bf16* __restrict__ q_ws,
                                                       const bf16* __restrict__ k_ws,
                                                       const bf16* __restrict__ vt_ws,
                                                       bf16* __restrict__ ctx) {
    __shared__ bf16 Ksm[2][64 * 64];       // 16 KB double-buffered K tile
    __shared__ bf16 Vsm[2][64 * 64];       // 16 KB double-buffered V^T tile
    __shared__ bf16 Pbuf[4][32 * kPSTR];   // 18 KB per-wave P slices -> 50 KB total

    const int idx = blockIdx.x;         // 0..1151; bh fastest -> idx%8 = bh%8 (XCD)
    const int bh  = idx % 96;
    const int qb  = idx / 96;           // 0..11, 128 Q rows per block
    const int b   = bh / kH;
    const int h   = bh - b * kH;
    const int tid  = threadIdx.x;
    const int w    = tid >> 6;
    const int lane = tid & 63;
    const int col  = lane & 15;         // q index within a 16-row tile
    const int quad = lane >> 4;
    const int q0   = qb * 128 + w * 32; // this wave's 32 Q rows (2 tiles)
    const bool active = (q0 < kS);      // wave-uniform; inactive waves still
                                        // stage + hit every barrier

    const bf16* qbase = q_ws  + (size_t)bh * kSP * kDH;
    const bf16* kbase = k_ws  + (size_t)bh * kSP * kDH;
    const bf16* vbase = vt_ws + (size_t)bh * kDH * kSP;

    bf16x8 qf[2][2] = {};
    if (active) {
#pragma unroll
        for (int qt = 0; qt < 2; qt++) {
            const bf16* qr = qbase + (size_t)(q0 + qt * 16 + col) * kDH + quad * 8;
            qf[qt][0] = *(const bf16x8*)(qr);
            qf[qt][1] = *(const bf16x8*)(qr + 32);
        }
    }

    float lsum[2] = {0.f, 0.f};
    floatx4 Oacc[2][4];
#pragma unroll
    for (int qt = 0; qt < 2; qt++)
#pragma unroll
        for (int n = 0; n < 4; n++) Oacc[qt][n] = (floatx4){0.f, 0.f, 0.f, 0.f};

    bf16* const P = &Pbuf[w][0];
    floatx4 sc[2][4];

    // prologue: stage chunk 0
    stage_k(kbase, 0, &Ksm[0][0], w, lane);
    stage_v(vbase, 0, &Vsm[0][0], w, lane);
    __syncthreads();

    int buf = 0;
    // chunks 0..22: stage next, compute current, one barrier per chunk
    for (int c = 0; c < 23; ++c) {
        stage_k(kbase, (c + 1) * 64, &Ksm[buf ^ 1][0], w, lane);
        stage_v(vbase, (c + 1) * 64, &Vsm[buf ^ 1][0], w, lane);
        if (active) {
            qk_mfma_lds(&Ksm[buf][0], qf, sc, col, quad);
            exp_store<false>(sc, P, lsum, c * 64, col, quad);
            pv_lds(&Vsm[buf][0], P, Oacc, col, quad);
        }
        __syncthreads();
        buf ^= 1;
    }
    // chunk 23 (keys 1472..1535; >=1500 masked to exact-zero P)
    if (active) {
        qk_mfma_lds(&Ksm[buf][0], qf, sc, col, quad);
        exp_store<true>(sc, P, lsum, 1472, col, quad);
        pv_lds(&Vsm[buf][0], P, Oacc, col, quad);

#pragma unroll
        for (int qt = 0; qt < 2; qt++) {
            float l = lsum[qt];
            l += __shfl_xor(l, 16);
            l += __shfl_xor(l, 32);
            const float rinv_col = 1.0f / l;         // for q = col of this tile
            float ri[4];
#pragma unroll
            for (int r = 0; r < 4; r++)
                ri[r] = __shfl(rinv_col, quad * 4 + r, 16);
#pragma unroll
            for (int n = 0; n < 4; n++)
#pragma unroll
                for (int r = 0; r < 4; r++) {
                    const int q = q0 + qt * 16 + quad * 4 + r;
                    if (q < kS)
                        ctx[((size_t)(b * kS + q)) * kD + h * kDH + n * 16 + col] =
                            (bf16)(Oacc[qt][n][r] * ri[r]);
                }
        }
    }
}

// ---------------------------------------------------------------------------
extern "C" void kernel_launch(void* const* d_in, const int* in_sizes, int n_in,
                              void* d_out, int out_size, void* d_ws, size_t ws_size,
                              hipStream_t stream) {
    float* out_f = (float*)d_out;   // reference output dtype is float32

    constexpr size_t nX = (size_t)kM * kD;
    constexpr size_t nW = (size_t)kD * kD;
    constexpr size_t per_qkv = (size_t)kB * kH * kSP * kDH;

    bf16* xb    = (bf16*)d_ws;
    bf16* Wqb   = xb + nX;
    bf16* Wkb   = Wqb + nW;
    bf16* Wvb   = Wkb + nW;
    bf16* Wob   = Wvb + nW;
    bf16* q_ws  = Wob + nW;
    bf16* k_ws  = q_ws + per_qkv;
    bf16* vt_ws = k_ws + per_qkv;
    float* bqf  = (float*)(vt_ws + per_qkv);
    float* bvf  = bqf + kD;
    float* bof  = bvf + kD;
    int*  flag  = (int*)(bof + kD);
    bf16* ctx   = xb;   // alias: xb last read by qkv_kernel, ctx written after

    // 1) dtype probe + input normalization to bf16 (biases to f32)
    detect_kernel<<<1, 256, 0, stream>>>(d_in[0], flag);
    cvt_bf16_kernel<<<(int)((nX + 255) / 256), 256, 0, stream>>>(d_in[0], xb,  (int)nX, flag);
    cvt_bf16_kernel<<<(int)((nW + 255) / 256), 256, 0, stream>>>(d_in[1], Wqb, (int)nW, flag);
    cvt_bf16_kernel<<<(int)((nW + 255) / 256), 256, 0, stream>>>(d_in[3], Wkb, (int)nW, flag);
    cvt_bf16_kernel<<<(int)((nW + 255) / 256), 256, 0, stream>>>(d_in[4], Wvb, (int)nW, flag);
    cvt_bf16_kernel<<<(int)((nW + 255) / 256), 256, 0, stream>>>(d_in[6], Wob, (int)nW, flag);
    cvt_f32_kernel<<<3, 256, 0, stream>>>(d_in[2], bqf, kD, flag);
    cvt_f32_kernel<<<3, 256, 0, stream>>>(d_in[5], bvf, kD, flag);
    cvt_f32_kernel<<<3, 256, 0, stream>>>(d_in[7], bof, kD, flag);

    // 2) fused QKV projection (+ padding): 1D grid 1696, XCD-pinned remap
    zeropad_kernel<<<96, 256, 0, stream>>>(q_ws, k_ws, vt_ws);
    qkv_kernel<<<dim3(1696), 256, 0, stream>>>(xb, Wqb, Wkb, Wvb, bqf, bvf,
                                               q_ws, k_ws, vt_ws);

    // 3) flash attention (1D grid: 12 q-blocks x 96 bh, bh fastest for XCD pin)
    fattn_kernel<<<dim3(12 * 96), 256, 0, stream>>>(q_ws, k_ws, vt_ws, ctx);

    // 4) output projection -> float32 d_out
    dim3 ogrid((kM + 127) / 128, kD / 128);   // 94 x 6
    out_kernel<<<ogrid, 256, 0, stream>>>(ctx, Wob, bof, out_f);
}

// Round 11
// 343.492 us; speedup vs baseline: 1.0373x; 1.0070x over previous
//
#include <hip/hip_runtime.h>
#include <hip/hip_bf16.h>

// Problem constants
constexpr int kD  = 768;
constexpr int kH  = 12;
constexpr int kDH = 64;
constexpr int kS  = 1500;
constexpr int kSP = 1504;        // S padded to multiple of 32 (47*32)
constexpr int kB  = 8;
constexpr int kM  = kB * kS;     // 12000 rows for the projections
constexpr float kScale = 0.125f;
constexpr int kPSTR = 72;        // P row stride (elems): 144B -> b64/b128 aligned
constexpr int kNK = kD / 32;     // 24 K-steps in the projections

typedef __bf16 bf16;
typedef __bf16 bf16x4 __attribute__((ext_vector_type(4)));
typedef __bf16 bf16x8 __attribute__((ext_vector_type(8)));
typedef float  floatx4 __attribute__((ext_vector_type(4)));

// ---------------------------------------------------------------------------
// Dtype probe (round-1 NaN proved inputs are f32; cheap guard retained).
// ---------------------------------------------------------------------------
__global__ __launch_bounds__(256) void detect_kernel(const void* __restrict__ xraw,
                                                     int* __restrict__ flag) {
    __shared__ int bad;
    if (threadIdx.x == 0) bad = 0;
    __syncthreads();
    const bf16* xb = (const bf16*)xraw;
    int c = 0;
    for (int k = 0; k < 16; k++) {
        int idx = 2 * (threadIdx.x + 256 * k);
        float v = fabsf((float)xb[idx]);
        if (!(v == 0.0f || (v > 1e-20f && v < 1e6f))) c++;
    }
    atomicAdd(&bad, c);
    __syncthreads();
    if (threadIdx.x == 0) *flag = (bad > 8) ? 1 : 0;
}

__global__ __launch_bounds__(256) void cvt_bf16_kernel(const void* __restrict__ src,
                                                       bf16* __restrict__ dst, int n,
                                                       const int* __restrict__ flag) {
    int i = blockIdx.x * 256 + threadIdx.x;
    if (i < n) {
        if (*flag)
            dst[i] = (bf16)((const float*)src)[i];
        else
            dst[i] = ((const bf16*)src)[i];
    }
}

__global__ __launch_bounds__(256) void cvt_f32_kernel(const void* __restrict__ src,
                                                      float* __restrict__ dst, int n,
                                                      const int* __restrict__ flag) {
    int i = blockIdx.x * 256 + threadIdx.x;
    if (i < n) {
        if (*flag)
            dst[i] = ((const float*)src)[i];
        else
            dst[i] = (float)((const bf16*)src)[i];
    }
}

// ---------------------------------------------------------------------------
// Zero the S-padding rows of q/k and padding cols of v^T.
// ---------------------------------------------------------------------------
__global__ __launch_bounds__(256) void zeropad_kernel(bf16* __restrict__ q_ws,
                                                      bf16* __restrict__ k_ws,
                                                      bf16* __restrict__ vt_ws) {
    int t = blockIdx.x * 256 + threadIdx.x;          // 96 bh * 4 s * 64 dh = 24576
    if (t < kB * kH * (kSP - kS) * kDH) {
        int bh  = t >> 8;
        int rem = t & 255;
        int s   = kS + (rem >> 6);
        int dh  = rem & 63;
        size_t qi = ((size_t)bh * kSP + s) * kDH + dh;
        q_ws[qi] = (bf16)0.f;
        k_ws[qi] = (bf16)0.f;
        size_t vi = ((size_t)bh * kDH + dh) * kSP + s;
        vt_ws[vi] = (bf16)0.f;
    }
}

// ---------------------------------------------------------------------------
// GEMM core (R6 known-good, resubmitted bit-for-bit for bisect): 128x128
// tile, BK=32, 4 waves, 4x4 acc/wave.
// TRIPLE-BUFFERED, 2-DEEP PREFETCH, COUNTED vmcnt(4):
//   iter k: STAGE(k+2 -> buf[(k+2)%3]); COMPUTE(buf[k%3]);
//           s_waitcnt vmcnt(4)  <- drains stage(k+1), issued a full iteration
//           earlier; stage(k+2) stays in flight across the barrier.
// ---------------------------------------------------------------------------
__device__ __forceinline__ void async_copy16(const bf16* g, bf16* l) {
    __builtin_amdgcn_global_load_lds(
        (const __attribute__((address_space(1))) void*)g,
        (__attribute__((address_space(3))) void*)l,
        16, 0, 0);
}

#define G_STAGE(KK, SB)                                                         \
    {                                                                           \
        const int k0_ = (KK) * 32;                                              \
        async_copy16(gA + k0_, Asm + (SB) * 4096 + wof);                        \
        async_copy16(gA + (size_t)64 * kD + k0_, Asm + (SB) * 4096 + wof + 2048); \
        async_copy16(gB + k0_, Bsm + (SB) * 4096 + wof);                        \
        async_copy16(gB + (size_t)64 * kD + k0_, Bsm + (SB) * 4096 + wof + 2048); \
    }

#define G_COMPUTE(CB)                                                           \
    {                                                                           \
        const bf16* A_ = Asm + (CB) * 4096;                                     \
        const bf16* B_ = Bsm + (CB) * 4096;                                     \
        bf16x8 af[4], bfr[4];                                                   \
        _Pragma("unroll") for (int i = 0; i < 4; i++)                           \
            af[i] = *(const bf16x8*)(A_ + ((wm + i * 16 + lrow) << 5) + (lq << 3)); \
        _Pragma("unroll") for (int j = 0; j < 4; j++)                           \
            bfr[j] = *(const bf16x8*)(B_ + ((wn + j * 16 + lrow) << 5) + (lq << 3)); \
        _Pragma("unroll") for (int i = 0; i < 4; i++)                           \
            _Pragma("unroll") for (int j = 0; j < 4; j++)                       \
                acc[i][j] = __builtin_amdgcn_mfma_f32_16x16x32_bf16(            \
                    af[i], bfr[j], acc[i][j], 0, 0, 0);                         \
    }

#define G_STEP(KK, CB, SB)                                                      \
    {                                                                           \
        if ((KK) + 2 < kNK) G_STAGE((KK) + 2, SB);                              \
        G_COMPUTE(CB);                                                          \
        if ((KK) + 1 < kNK) {                                                   \
            if ((KK) + 2 < kNK) {                                               \
                asm volatile("s_waitcnt vmcnt(4)" ::: "memory");                \
            } else {                                                            \
                asm volatile("s_waitcnt vmcnt(0)" ::: "memory");                \
            }                                                                   \
            __builtin_amdgcn_s_barrier();                                       \
            __builtin_amdgcn_sched_barrier(0);                                  \
        }                                                                       \
    }

__device__ __forceinline__ void gemm128_tb(const bf16* __restrict__ X,
                                           const bf16* __restrict__ W,
                                           int m0, int n0,
                                           bf16* Asm, bf16* Bsm,   // [3][4096] each
                                           floatx4 acc[4][4]) {
    const int tid  = threadIdx.x;
    const int lane = tid & 63;
    const int w    = tid >> 6;
    const int srow = (w << 4) + (lane >> 2);
    const int scol = (lane & 3) << 3;
    const int lrow = lane & 15;
    const int lq   = lane >> 4;
    const int wm   = (w >> 1) << 6;
    const int wn   = (w & 1) << 6;

    const bf16* gA = X + (size_t)(m0 + srow) * kD + scol;
    const bf16* gB = W + (size_t)(n0 + srow) * kD + scol;
    const int wof = w << 9;      // wave-uniform LDS base; HW adds lane*16B

    // prologue: stage K-steps 0,1 into buffers 0,1; wait only for step 0
    G_STAGE(0, 0);
    G_STAGE(1, 1);
    asm volatile("s_waitcnt vmcnt(4)" ::: "memory");
    __builtin_amdgcn_s_barrier();
    __builtin_amdgcn_sched_barrier(0);

#pragma unroll
    for (int ks = 0; ks < kNK; ks += 3) {
        G_STEP(ks,     0, 2);
        G_STEP(ks + 1, 1, 0);
        G_STEP(ks + 2, 2, 1);
    }
}

// Fused QKV projection. 1D grid of 1696 with XCD-pinned work remap:
// wk = (lin&7)*212 + lin>>3 puts all 18 (mat,n0)-blocks of one X-slab on
// ONE XCD (kept: R5 FETCH 102->53 MB). 4 dummy blocks return pre-barrier.
// Epilogue: R6 known-good scalar stores (the vectorized LDS-staged epilogue
// of R7-R10 correlated with 4 consecutive harness failures; dropped).
__global__ __launch_bounds__(256) void qkv_kernel(const bf16* __restrict__ X,
                                                  const bf16* __restrict__ Wq,
                                                  const bf16* __restrict__ Wk,
                                                  const bf16* __restrict__ Wv,
                                                  const float* __restrict__ bq,
                                                  const float* __restrict__ bv,
                                                  bf16* __restrict__ q_ws,
                                                  bf16* __restrict__ k_ws,
                                                  bf16* __restrict__ vt_ws) {
    __shared__ bf16 Asm[3 * 4096];
    __shared__ bf16 Bsm[3 * 4096];

    const int lin = blockIdx.x;
    const int wk  = (lin & 7) * 212 + (lin >> 3);
    if (wk >= 94 * 18) return;
    const int bx  = wk / 18;
    const int r   = wk - bx * 18;
    const int m0  = bx << 7;
    const int mat = r / 6;
    const int n0  = (r % 6) << 7;
    const bf16* W = (mat == 0) ? Wq : (mat == 1) ? Wk : Wv;

    floatx4 acc[4][4] = {};
    gemm128_tb(X, W, m0, n0, Asm, Bsm, acc);

    const int tid  = threadIdx.x;
    const int lane = tid & 63;
    const int w    = tid >> 6;
    const int lrow = lane & 15;
    const int lq   = lane >> 4;
    const int wm   = (w >> 1) << 6;
    const int wn   = (w & 1) << 6;

#pragma unroll
    for (int i = 0; i < 4; i++) {
#pragma unroll
        for (int j = 0; j < 4; j++) {
            const int n  = n0 + wn + j * 16 + lrow;
            const int hh = n >> 6, dh = n & 63;
            const float bval = (mat == 0) ? bq[n] : (mat == 2) ? bv[n] : 0.f;
#pragma unroll
            for (int r2 = 0; r2 < 4; r2++) {
                const int m = m0 + wm + i * 16 + lq * 4 + r2;
                if (m >= kM) continue;
                float v = acc[i][j][r2];
                if (mat == 0)      v = (v + bval) * kScale;
                else if (mat == 2) v = v + bval;
                const int bb = m / kS, s = m - bb * kS;
                if (mat == 2)
                    vt_ws[(((size_t)(bb * kH + hh)) * kDH + dh) * kSP + s] = (bf16)v;
                else if (mat == 1)
                    k_ws[(((size_t)(bb * kH + hh)) * kSP + s) * kDH + dh] = (bf16)v;
                else
                    q_ws[(((size_t)(bb * kH + hh)) * kSP + s) * kDH + dh] = (bf16)v;
            }
        }
    }
}

__global__ __launch_bounds__(256) void out_kernel(const bf16* __restrict__ X,
                                                  const bf16* __restrict__ Wo,
                                                  const float* __restrict__ bo,
                                                  float* __restrict__ outf) {
    __shared__ bf16 Asm[3 * 4096];
    __shared__ bf16 Bsm[3 * 4096];

    const int m0 = blockIdx.x << 7;
    const int n0 = blockIdx.y << 7;

    floatx4 acc[4][4] = {};
    gemm128_tb(X, Wo, m0, n0, Asm, Bsm, acc);

    const int tid  = threadIdx.x;
    const int lane = tid & 63;
    const int w    = tid >> 6;
    const int lrow = lane & 15;
    const int lq   = lane >> 4;
    const int wm   = (w >> 1) << 6;
    const int wn   = (w & 1) << 6;

#pragma unroll
    for (int i = 0; i < 4; i++) {
#pragma unroll
        for (int j = 0; j < 4; j++) {
            const int n = n0 + wn + j * 16 + lrow;
            const float bval = bo[n];
#pragma unroll
            for (int r = 0; r < 4; r++) {
                const int m = m0 + wm + i * 16 + lq * 4 + r;
                if (m >= kM) continue;
                outf[(size_t)m * kD + n] = acc[i][j][r] + bval;
            }
        }
    }
}

// ---------------------------------------------------------------------------
// Flash attention v7 (UNCHANGED, known-good): K/V staged in LDS via
// global_load_lds, double-buffered, shared by all 4 waves; XOR bank swizzle
// (linear LDS dest + inverse-swizzled global source + swizzled read).
// ---------------------------------------------------------------------------
__device__ __forceinline__ const bf16* lds_at(const bf16* sm, int row, int cb) {
    // row-major [64][128B] tile with XOR bank swizzle on the byte column
    return sm + row * 64 + ((cb ^ ((row & 7) << 4)) >> 1);
}

__device__ __forceinline__ void stage_k(const bf16* __restrict__ kbase, int s0,
                                        bf16* ksm, int w, int lane) {
#pragma unroll
    for (int i = 0; i < 2; i++) {
        const int sidx = i * 4 + w;
        const int row  = sidx * 8 + (lane >> 3);
        const int cb   = (lane & 7) << 4;
        const int scb  = cb ^ ((row & 7) << 4);
        int gr = s0 + row;
        if (gr >= kSP) gr = 1472;                    // tail clamp (finite data)
        async_copy16(kbase + (size_t)gr * kDH + (scb >> 1), ksm + sidx * 512);
    }
}

__device__ __forceinline__ void stage_v(const bf16* __restrict__ vbase, int s0,
                                        bf16* vsm, int w, int lane) {
#pragma unroll
    for (int i = 0; i < 2; i++) {
        const int sidx = i * 4 + w;
        const int row  = sidx * 8 + (lane >> 3);     // dh
        const int cb   = (lane & 7) << 4;
        const int scb  = cb ^ ((row & 7) << 4);
        int key = s0 + (scb >> 1);
        if (key >= kSP) key = 1472;                  // tail clamp (finite data)
        async_copy16(vbase + (size_t)row * kSP + key, vsm + sidx * 512);
    }
}

__device__ __forceinline__ void qk_mfma_lds(const bf16* ksm,
                                            const bf16x8 qf[2][2],
                                            floatx4 sc[2][4],
                                            int col, int quad) {
#pragma unroll
    for (int t = 0; t < 4; t++) {
        const int r = 16 * t + col;
        const bf16x8 kf0 = *(const bf16x8*)lds_at(ksm, r, quad * 16);
        const bf16x8 kf1 = *(const bf16x8*)lds_at(ksm, r, 64 + quad * 16);
        __builtin_amdgcn_s_setprio(1);
#pragma unroll
        for (int qt = 0; qt < 2; qt++) {
            floatx4 a = {0.f, 0.f, 0.f, 0.f};
            a = __builtin_amdgcn_mfma_f32_16x16x32_bf16(kf0, qf[qt][0], a, 0, 0, 0);
            a = __builtin_amdgcn_mfma_f32_16x16x32_bf16(kf1, qf[qt][1], a, 0, 0, 0);
            sc[qt][t] = a;
        }
        __builtin_amdgcn_s_setprio(0);
    }
}

template <bool MASK>
__device__ __forceinline__ void exp_store(const floatx4 sc[2][4],
                                          bf16* __restrict__ Pw,
                                          float lsum[2],
                                          int s0, int col, int quad) {
#pragma unroll
    for (int qt = 0; qt < 2; qt++)
#pragma unroll
        for (int t = 0; t < 4; t++) {
            bf16x4 pv;
#pragma unroll
            for (int r = 0; r < 4; r++) {
                float p;
                if (MASK && (s0 + 16 * t + quad * 4 + r >= kS))
                    p = 0.f;
                else
                    p = __expf(sc[qt][t][r]);
                lsum[qt] += p;
                pv[r] = (bf16)p;
            }
            *(bf16x4*)(Pw + (qt * 16 + col) * kPSTR + 16 * t + quad * 4) = pv;
        }
}

__device__ __forceinline__ void pv_lds(const bf16* vsm,
                                       const bf16* __restrict__ Pr,
                                       floatx4 Oacc[2][4],
                                       int col, int quad) {
    bf16x8 pa[2][2];
#pragma unroll
    for (int qt = 0; qt < 2; qt++)
#pragma unroll
        for (int kc = 0; kc < 2; kc++)
            pa[qt][kc] = *(const bf16x8*)(Pr + (qt * 16 + col) * kPSTR + kc * 32 + quad * 8);
#pragma unroll
    for (int n = 0; n < 4; n++) {
        const int row = n * 16 + col;                // dh row of V^T tile
#pragma unroll
        for (int kc = 0; kc < 2; kc++) {
            const bf16x8 vf = *(const bf16x8*)lds_at(vsm, row, kc * 64 + quad * 16);
            __builtin_amdgcn_s_setprio(1);
#pragma unroll
            for (int qt = 0; qt < 2; qt++)
                Oacc[qt][n] = __builtin_amdgcn_mfma_f32_16x16x32_bf16(
                    pa[qt][kc], vf, Oacc[qt][n], 0, 0, 0);
            __builtin_amdgcn_s_setprio(0);
        }
    }
}

__global__ __launch_bounds__(256, 2) void fattn_kernel(const bf16* __restrict__ q_ws,
                                                       const bf16* __restrict__ k_ws,
                                                       const bf16* __restrict__ vt_ws,
                                                       bf16* __restrict__ ctx) {
    __shared__ bf16 Ksm[2][64 * 64];       // 16 KB double-buffered K tile
    __shared__ bf16 Vsm[2][64 * 64];       // 16 KB double-buffered V^T tile
    __shared__ bf16 Pbuf[4][32 * kPSTR];   // 18 KB per-wave P slices -> 50 KB total

    const int idx = blockIdx.x;         // 0..1151; bh fastest -> idx%8 = bh%8 (XCD)
    const int bh  = idx % 96;
    const int qb  = idx / 96;           // 0..11, 128 Q rows per block
    const int b   = bh / kH;
    const int h   = bh - b * kH;
    const int tid  = threadIdx.x;
    const int w    = tid >> 6;
    const int lane = tid & 63;
    const int col  = lane & 15;         // q index within a 16-row tile
    const int quad = lane >> 4;
    const int q0   = qb * 128 + w * 32; // this wave's 32 Q rows (2 tiles)
    const bool active = (q0 < kS);      // wave-uniform; inactive waves still
                                        // stage + hit every barrier

    const bf16* qbase = q_ws  + (size_t)bh * kSP * kDH;
    const bf16* kbase = k_ws  + (size_t)bh * kSP * kDH;
    const bf16* vbase = vt_ws + (size_t)bh * kDH * kSP;

    bf16x8 qf[2][2] = {};
    if (active) {
#pragma unroll
        for (int qt = 0; qt < 2; qt++) {
            const bf16* qr = qbase + (size_t)(q0 + qt * 16 + col) * kDH + quad * 8;
            qf[qt][0] = *(const bf16x8*)(qr);
            qf[qt][1] = *(const bf16x8*)(qr + 32);
        }
    }

    float lsum[2] = {0.f, 0.f};
    floatx4 Oacc[2][4];
#pragma unroll
    for (int qt = 0; qt < 2; qt++)
#pragma unroll
        for (int n = 0; n < 4; n++) Oacc[qt][n] = (floatx4){0.f, 0.f, 0.f, 0.f};

    bf16* const P = &Pbuf[w][0];
    floatx4 sc[2][4];

    // prologue: stage chunk 0
    stage_k(kbase, 0, &Ksm[0][0], w, lane);
    stage_v(vbase, 0, &Vsm[0][0], w, lane);
    __syncthreads();

    int buf = 0;
    // chunks 0..22: stage next, compute current, one barrier per chunk
    for (int c = 0; c < 23; ++c) {
        stage_k(kbase, (c + 1) * 64, &Ksm[buf ^ 1][0], w, lane);
        stage_v(vbase, (c + 1) * 64, &Vsm[buf ^ 1][0], w, lane);
        if (active) {
            qk_mfma_lds(&Ksm[buf][0], qf, sc, col, quad);
            exp_store<false>(sc, P, lsum, c * 64, col, quad);
            pv_lds(&Vsm[buf][0], P, Oacc, col, quad);
        }
        __syncthreads();
        buf ^= 1;
    }
    // chunk 23 (keys 1472..1535; >=1500 masked to exact-zero P)
    if (active) {
        qk_mfma_lds(&Ksm[buf][0], qf, sc, col, quad);
        exp_store<true>(sc, P, lsum, 1472, col, quad);
        pv_lds(&Vsm[buf][0], P, Oacc, col, quad);

#pragma unroll
        for (int qt = 0; qt < 2; qt++) {
            float l = lsum[qt];
            l += __shfl_xor(l, 16);
            l += __shfl_xor(l, 32);
            const float rinv_col = 1.0f / l;         // for q = col of this tile
            float ri[4];
#pragma unroll
            for (int r = 0; r < 4; r++)
                ri[r] = __shfl(rinv_col, quad * 4 + r, 16);
#pragma unroll
            for (int n = 0; n < 4; n++)
#pragma unroll
                for (int r = 0; r < 4; r++) {
                    const int q = q0 + qt * 16 + quad * 4 + r;
                    if (q < kS)
                        ctx[((size_t)(b * kS + q)) * kD + h * kDH + n * 16 + col] =
                            (bf16)(Oacc[qt][n][r] * ri[r]);
                }
        }
    }
}

// ---------------------------------------------------------------------------
extern "C" void kernel_launch(void* const* d_in, const int* in_sizes, int n_in,
                              void* d_out, int out_size, void* d_ws, size_t ws_size,
                              hipStream_t stream) {
    float* out_f = (float*)d_out;   // reference output dtype is float32

    constexpr size_t nX = (size_t)kM * kD;
    constexpr size_t nW = (size_t)kD * kD;
    constexpr size_t per_qkv = (size_t)kB * kH * kSP * kDH;

    bf16* xb    = (bf16*)d_ws;
    bf16* Wqb   = xb + nX;
    bf16* Wkb   = Wqb + nW;
    bf16* Wvb   = Wkb + nW;
    bf16* Wob   = Wvb + nW;
    bf16* q_ws  = Wob + nW;
    bf16* k_ws  = q_ws + per_qkv;
    bf16* vt_ws = k_ws + per_qkv;
    float* bqf  = (float*)(vt_ws + per_qkv);
    float* bvf  = bqf + kD;
    float* bof  = bvf + kD;
    int*  flag  = (int*)(bof + kD);
    bf16* ctx   = xb;   // alias: xb last read by qkv_kernel, ctx written after

    // 1) dtype probe + input normalization to bf16 (biases to f32)
    detect_kernel<<<1, 256, 0, stream>>>(d_in[0], flag);
    cvt_bf16_kernel<<<(int)((nX + 255) / 256), 256, 0, stream>>>(d_in[0], xb,  (int)nX, flag);
    cvt_bf16_kernel<<<(int)((nW + 255) / 256), 256, 0, stream>>>(d_in[1], Wqb, (int)nW, flag);
    cvt_bf16_kernel<<<(int)((nW + 255) / 256), 256, 0, stream>>>(d_in[3], Wkb, (int)nW, flag);
    cvt_bf16_kernel<<<(int)((nW + 255) / 256), 256, 0, stream>>>(d_in[4], Wvb, (int)nW, flag);
    cvt_bf16_kernel<<<(int)((nW + 255) / 256), 256, 0, stream>>>(d_in[6], Wob, (int)nW, flag);
    cvt_f32_kernel<<<3, 256, 0, stream>>>(d_in[2], bqf, kD, flag);
    cvt_f32_kernel<<<3, 256, 0, stream>>>(d_in[5], bvf, kD, flag);
    cvt_f32_kernel<<<3, 256, 0, stream>>>(d_in[7], bof, kD, flag);

    // 2) fused QKV projection (+ padding): 1D grid 1696, XCD-pinned remap
    zeropad_kernel<<<96, 256, 0, stream>>>(q_ws, k_ws, vt_ws);
    qkv_kernel<<<dim3(1696), 256, 0, stream>>>(xb, Wqb, Wkb, Wvb, bqf, bvf,
                                               q_ws, k_ws, vt_ws);

    // 3) flash attention (1D grid: 12 q-blocks x 96 bh, bh fastest for XCD pin)
    fattn_kernel<<<dim3(12 * 96), 256, 0, stream>>>(q_ws, k_ws, vt_ws, ctx);

    // 4) output projection -> float32 d_out
    dim3 ogrid((kM + 127) / 128, kD / 128);   // 94 x 6
    out_kernel<<<ogrid, 256, 0, stream>>>(ctx, Wob, bof, out_f);
}

// Round 12
// 339.078 us; speedup vs baseline: 1.0508x; 1.0130x over previous
//
#include <hip/hip_runtime.h>
#include <hip/hip_bf16.h>

// Problem constants
constexpr int kD  = 768;
constexpr int kH  = 12;
constexpr int kDH = 64;
constexpr int kS  = 1500;
constexpr int kSP = 1504;        // S padded to multiple of 32 (47*32)
constexpr int kB  = 8;
constexpr int kM  = kB * kS;     // 12000 rows for the projections
constexpr float kScale = 0.125f;
constexpr int kPSTR = 72;        // P row stride (elems): 144B -> b64/b128 aligned
constexpr int kNK = kD / 32;     // 24 K-steps in the projections

typedef __bf16 bf16;
typedef __bf16 bf16x4 __attribute__((ext_vector_type(4)));
typedef __bf16 bf16x8 __attribute__((ext_vector_type(8)));
typedef float  floatx4 __attribute__((ext_vector_type(4)));

// ---------------------------------------------------------------------------
// Dtype probe (round-1 NaN proved inputs are f32; cheap guard retained).
// ---------------------------------------------------------------------------
__global__ __launch_bounds__(256) void detect_kernel(const void* __restrict__ xraw,
                                                     int* __restrict__ flag) {
    __shared__ int bad;
    if (threadIdx.x == 0) bad = 0;
    __syncthreads();
    const bf16* xb = (const bf16*)xraw;
    int c = 0;
    for (int k = 0; k < 16; k++) {
        int idx = 2 * (threadIdx.x + 256 * k);
        float v = fabsf((float)xb[idx]);
        if (!(v == 0.0f || (v > 1e-20f && v < 1e6f))) c++;
    }
    atomicAdd(&bad, c);
    __syncthreads();
    if (threadIdx.x == 0) *flag = (bad > 8) ? 1 : 0;
}

__global__ __launch_bounds__(256) void cvt_bf16_kernel(const void* __restrict__ src,
                                                       bf16* __restrict__ dst, int n,
                                                       const int* __restrict__ flag) {
    int i = blockIdx.x * 256 + threadIdx.x;
    if (i < n) {
        if (*flag)
            dst[i] = (bf16)((const float*)src)[i];
        else
            dst[i] = ((const bf16*)src)[i];
    }
}

__global__ __launch_bounds__(256) void cvt_f32_kernel(const void* __restrict__ src,
                                                      float* __restrict__ dst, int n,
                                                      const int* __restrict__ flag) {
    int i = blockIdx.x * 256 + threadIdx.x;
    if (i < n) {
        if (*flag)
            dst[i] = ((const float*)src)[i];
        else
            dst[i] = (float)((const bf16*)src)[i];
    }
}

// ---------------------------------------------------------------------------
// Zero the S-padding rows of q/k and padding cols of v^T.
// ---------------------------------------------------------------------------
__global__ __launch_bounds__(256) void zeropad_kernel(bf16* __restrict__ q_ws,
                                                      bf16* __restrict__ k_ws,
                                                      bf16* __restrict__ vt_ws) {
    int t = blockIdx.x * 256 + threadIdx.x;          // 96 bh * 4 s * 64 dh = 24576
    if (t < kB * kH * (kSP - kS) * kDH) {
        int bh  = t >> 8;
        int rem = t & 255;
        int s   = kS + (rem >> 6);
        int dh  = rem & 63;
        size_t qi = ((size_t)bh * kSP + s) * kDH + dh;
        q_ws[qi] = (bf16)0.f;
        k_ws[qi] = (bf16)0.f;
        size_t vi = ((size_t)bh * kDH + dh) * kSP + s;
        vt_ws[vi] = (bf16)0.f;
    }
}

// ---------------------------------------------------------------------------
// GEMM core v4 (re-applied; R7/R8 crashes root-caused to the misaligned V^T
// epilogue store, not this core): 128x128 tile, BK=32, 4 waves, 4x4 acc.
// QUAD-BUFFERED, 3-DEEP PREFETCH, vmcnt(8) steady state:
//   iter k: STAGE(k+3 -> buf[(k+3)%4]); COMPUTE(buf[k%4]);
//           s_waitcnt vmcnt(8)  <- drains stage(k+1), issued TWO iterations
//           ago (~2 compute-iters of cover >= HBM ~900cy; R6's 2-deep only
//           covered L2). stages k+2,k+3 stay in flight across the barrier.
// Ledger: outstanding at wait = {k+1,k+2,k+3} = 12 loads; vmcnt(8) drains
// exactly k+1; buf (k+4)%4 == buf k%4 overwritten only after the iter-k
// barrier on all waves; tail k=21/22 -> vmcnt(4)/vmcnt(0).
// ---------------------------------------------------------------------------
__device__ __forceinline__ void async_copy16(const bf16* g, bf16* l) {
    __builtin_amdgcn_global_load_lds(
        (const __attribute__((address_space(1))) void*)g,
        (__attribute__((address_space(3))) void*)l,
        16, 0, 0);
}

#define G_STAGE(KK, SB)                                                         \
    {                                                                           \
        const int k0_ = (KK) * 32;                                              \
        async_copy16(gA + k0_, Asm + (SB) * 4096 + wof);                        \
        async_copy16(gA + (size_t)64 * kD + k0_, Asm + (SB) * 4096 + wof + 2048); \
        async_copy16(gB + k0_, Bsm + (SB) * 4096 + wof);                        \
        async_copy16(gB + (size_t)64 * kD + k0_, Bsm + (SB) * 4096 + wof + 2048); \
    }

#define G_COMPUTE(CB)                                                           \
    {                                                                           \
        const bf16* A_ = Asm + (CB) * 4096;                                     \
        const bf16* B_ = Bsm + (CB) * 4096;                                     \
        bf16x8 af[4], bfr[4];                                                   \
        _Pragma("unroll") for (int i = 0; i < 4; i++)                           \
            af[i] = *(const bf16x8*)(A_ + ((wm + i * 16 + lrow) << 5) + (lq << 3)); \
        _Pragma("unroll") for (int j = 0; j < 4; j++)                           \
            bfr[j] = *(const bf16x8*)(B_ + ((wn + j * 16 + lrow) << 5) + (lq << 3)); \
        _Pragma("unroll") for (int i = 0; i < 4; i++)                           \
            _Pragma("unroll") for (int j = 0; j < 4; j++)                       \
                acc[i][j] = __builtin_amdgcn_mfma_f32_16x16x32_bf16(            \
                    af[i], bfr[j], acc[i][j], 0, 0, 0);                         \
    }

#define G_STEP(KK, CB, SB)                                                      \
    {                                                                           \
        if ((KK) + 3 < kNK) G_STAGE((KK) + 3, SB);                              \
        G_COMPUTE(CB);                                                          \
        if ((KK) + 1 < kNK) {                                                   \
            if ((KK) + 3 < kNK) {                                               \
                asm volatile("s_waitcnt vmcnt(8)" ::: "memory");                \
            } else if ((KK) + 2 < kNK) {                                        \
                asm volatile("s_waitcnt vmcnt(4)" ::: "memory");                \
            } else {                                                            \
                asm volatile("s_waitcnt vmcnt(0)" ::: "memory");                \
            }                                                                   \
            __builtin_amdgcn_s_barrier();                                       \
            __builtin_amdgcn_sched_barrier(0);                                  \
        }                                                                       \
    }

__device__ __forceinline__ void gemm128_qb(const bf16* __restrict__ X,
                                           const bf16* __restrict__ W,
                                           int m0, int n0,
                                           bf16* Asm, bf16* Bsm,   // [4][4096] each
                                           floatx4 acc[4][4]) {
    const int tid  = threadIdx.x;
    const int lane = tid & 63;
    const int w    = tid >> 6;
    const int srow = (w << 4) + (lane >> 2);
    const int scol = (lane & 3) << 3;
    const int lrow = lane & 15;
    const int lq   = lane >> 4;
    const int wm   = (w >> 1) << 6;
    const int wn   = (w & 1) << 6;

    const bf16* gA = X + (size_t)(m0 + srow) * kD + scol;
    const bf16* gB = W + (size_t)(n0 + srow) * kD + scol;
    const int wof = w << 9;      // wave-uniform LDS base; HW adds lane*16B

    // prologue: stage K-steps 0,1,2 into buffers 0,1,2; drain only step 0
    G_STAGE(0, 0);
    G_STAGE(1, 1);
    G_STAGE(2, 2);
    asm volatile("s_waitcnt vmcnt(8)" ::: "memory");
    __builtin_amdgcn_s_barrier();
    __builtin_amdgcn_sched_barrier(0);

#pragma unroll
    for (int ks = 0; ks < kNK; ks += 4) {
        G_STEP(ks,     0, 3);
        G_STEP(ks + 1, 1, 0);
        G_STEP(ks + 2, 2, 1);
        G_STEP(ks + 3, 3, 2);
    }
}

// Fused QKV projection. 1D grid 1696, XCD-pinned remap (FETCH 102->53MB).
// Epilogue: mat0/1 keep R6/R11 known-good scalar stores (32B segments).
// mat2 (V^T) NEW: acc r-dim is m-contiguous -> pack acc[i][j][0..3] into ONE
// bf16x4 (8B) store of 4 consecutive s. Replaces 64 scalar 2B stores/thread
// (16-line scatter per wave-instr) with 16 packed 8B stores. Alignment
// proof: m ≡ 0 mod 4 and 1500 ≡ 0 mod 4 -> s ≡ 0 mod 4 -> byte ≡ 0 mod 8;
// a 4-run never crosses a batch boundary (s+3 <= 1499); m < kM with
// m ≡ 0 mod 4 implies m+3 <= 11999. No fallback path needed.
__global__ __launch_bounds__(256) void qkv_kernel(const bf16* __restrict__ X,
                                                  const bf16* __restrict__ Wq,
                                                  const bf16* __restrict__ Wk,
                                                  const bf16* __restrict__ Wv,
                                                  const float* __restrict__ bq,
                                                  const float* __restrict__ bv,
                                                  bf16* __restrict__ q_ws,
                                                  bf16* __restrict__ k_ws,
                                                  bf16* __restrict__ vt_ws) {
    __shared__ bf16 Asm[4 * 4096];
    __shared__ bf16 Bsm[4 * 4096];

    const int lin = blockIdx.x;
    const int wk  = (lin & 7) * 212 + (lin >> 3);
    if (wk >= 94 * 18) return;
    const int bx  = wk / 18;
    const int r   = wk - bx * 18;
    const int m0  = bx << 7;
    const int mat = r / 6;
    const int n0  = (r % 6) << 7;
    const bf16* W = (mat == 0) ? Wq : (mat == 1) ? Wk : Wv;

    floatx4 acc[4][4] = {};
    gemm128_qb(X, W, m0, n0, Asm, Bsm, acc);

    const int tid  = threadIdx.x;
    const int lane = tid & 63;
    const int w    = tid >> 6;
    const int lrow = lane & 15;
    const int lq   = lane >> 4;
    const int wm   = (w >> 1) << 6;
    const int wn   = (w & 1) << 6;

    if (mat == 2) {
#pragma unroll
        for (int i = 0; i < 4; i++) {
#pragma unroll
            for (int j = 0; j < 4; j++) {
                const int n  = n0 + wn + j * 16 + lrow;
                const int hh = n >> 6, dh = n & 63;
                const float bval = bv[n];
                const int m = m0 + wm + i * 16 + lq * 4;
                if (m >= kM) continue;               // m ≡ 0 mod 4 -> m+3 < kM
                const int bb = m / kS, s = m - bb * kS;
                bf16x4 pv;
#pragma unroll
                for (int r2 = 0; r2 < 4; r2++) pv[r2] = (bf16)(acc[i][j][r2] + bval);
                *(bf16x4*)(vt_ws + (((size_t)(bb * kH + hh)) * kDH + dh) * kSP + s) = pv;
            }
        }
    } else {
        bf16* const dst = (mat == 0) ? q_ws : k_ws;
#pragma unroll
        for (int i = 0; i < 4; i++) {
#pragma unroll
            for (int j = 0; j < 4; j++) {
                const int n  = n0 + wn + j * 16 + lrow;
                const int hh = n >> 6, dh = n & 63;
                const float bval = (mat == 0) ? bq[n] : 0.f;
#pragma unroll
                for (int r2 = 0; r2 < 4; r2++) {
                    const int m = m0 + wm + i * 16 + lq * 4 + r2;
                    if (m >= kM) continue;
                    float v = acc[i][j][r2];
                    if (mat == 0) v = (v + bval) * kScale;
                    const int bb = m / kS, s = m - bb * kS;
                    dst[(((size_t)(bb * kH + hh)) * kSP + s) * kDH + dh] = (bf16)v;
                }
            }
        }
    }
}

__global__ __launch_bounds__(256) void out_kernel(const bf16* __restrict__ X,
                                                  const bf16* __restrict__ Wo,
                                                  const float* __restrict__ bo,
                                                  float* __restrict__ outf) {
    __shared__ bf16 Asm[4 * 4096];
    __shared__ bf16 Bsm[4 * 4096];

    const int m0 = blockIdx.x << 7;
    const int n0 = blockIdx.y << 7;

    floatx4 acc[4][4] = {};
    gemm128_qb(X, Wo, m0, n0, Asm, Bsm, acc);

    const int tid  = threadIdx.x;
    const int lane = tid & 63;
    const int w    = tid >> 6;
    const int lrow = lane & 15;
    const int lq   = lane >> 4;
    const int wm   = (w >> 1) << 6;
    const int wn   = (w & 1) << 6;

#pragma unroll
    for (int i = 0; i < 4; i++) {
#pragma unroll
        for (int j = 0; j < 4; j++) {
            const int n = n0 + wn + j * 16 + lrow;
            const float bval = bo[n];
#pragma unroll
            for (int r = 0; r < 4; r++) {
                const int m = m0 + wm + i * 16 + lq * 4 + r;
                if (m >= kM) continue;
                outf[(size_t)m * kD + n] = acc[i][j][r] + bval;
            }
        }
    }
}

// ---------------------------------------------------------------------------
// Flash attention v7 (UNCHANGED, known-good): K/V staged in LDS via
// global_load_lds, double-buffered, shared by all 4 waves; XOR bank swizzle
// (linear LDS dest + inverse-swizzled global source + swizzled read).
// ---------------------------------------------------------------------------
__device__ __forceinline__ const bf16* lds_at(const bf16* sm, int row, int cb) {
    // row-major [64][128B] tile with XOR bank swizzle on the byte column
    return sm + row * 64 + ((cb ^ ((row & 7) << 4)) >> 1);
}

__device__ __forceinline__ void stage_k(const bf16* __restrict__ kbase, int s0,
                                        bf16* ksm, int w, int lane) {
#pragma unroll
    for (int i = 0; i < 2; i++) {
        const int sidx = i * 4 + w;
        const int row  = sidx * 8 + (lane >> 3);
        const int cb   = (lane & 7) << 4;
        const int scb  = cb ^ ((row & 7) << 4);
        int gr = s0 + row;
        if (gr >= kSP) gr = 1472;                    // tail clamp (finite data)
        async_copy16(kbase + (size_t)gr * kDH + (scb >> 1), ksm + sidx * 512);
    }
}

__device__ __forceinline__ void stage_v(const bf16* __restrict__ vbase, int s0,
                                        bf16* vsm, int w, int lane) {
#pragma unroll
    for (int i = 0; i < 2; i++) {
        const int sidx = i * 4 + w;
        const int row  = sidx * 8 + (lane >> 3);     // dh
        const int cb   = (lane & 7) << 4;
        const int scb  = cb ^ ((row & 7) << 4);
        int key = s0 + (scb >> 1);
        if (key >= kSP) key = 1472;                  // tail clamp (finite data)
        async_copy16(vbase + (size_t)row * kSP + key, vsm + sidx * 512);
    }
}

__device__ __forceinline__ void qk_mfma_lds(const bf16* ksm,
                                            const bf16x8 qf[2][2],
                                            floatx4 sc[2][4],
                                            int col, int quad) {
#pragma unroll
    for (int t = 0; t < 4; t++) {
        const int r = 16 * t + col;
        const bf16x8 kf0 = *(const bf16x8*)lds_at(ksm, r, quad * 16);
        const bf16x8 kf1 = *(const bf16x8*)lds_at(ksm, r, 64 + quad * 16);
        __builtin_amdgcn_s_setprio(1);
#pragma unroll
        for (int qt = 0; qt < 2; qt++) {
            floatx4 a = {0.f, 0.f, 0.f, 0.f};
            a = __builtin_amdgcn_mfma_f32_16x16x32_bf16(kf0, qf[qt][0], a, 0, 0, 0);
            a = __builtin_amdgcn_mfma_f32_16x16x32_bf16(kf1, qf[qt][1], a, 0, 0, 0);
            sc[qt][t] = a;
        }
        __builtin_amdgcn_s_setprio(0);
    }
}

template <bool MASK>
__device__ __forceinline__ void exp_store(const floatx4 sc[2][4],
                                          bf16* __restrict__ Pw,
                                          float lsum[2],
                                          int s0, int col, int quad) {
#pragma unroll
    for (int qt = 0; qt < 2; qt++)
#pragma unroll
        for (int t = 0; t < 4; t++) {
            bf16x4 pv;
#pragma unroll
            for (int r = 0; r < 4; r++) {
                float p;
                if (MASK && (s0 + 16 * t + quad * 4 + r >= kS))
                    p = 0.f;
                else
                    p = __expf(sc[qt][t][r]);
                lsum[qt] += p;
                pv[r] = (bf16)p;
            }
            *(bf16x4*)(Pw + (qt * 16 + col) * kPSTR + 16 * t + quad * 4) = pv;
        }
}

__device__ __forceinline__ void pv_lds(const bf16* vsm,
                                       const bf16* __restrict__ Pr,
                                       floatx4 Oacc[2][4],
                                       int col, int quad) {
    bf16x8 pa[2][2];
#pragma unroll
    for (int qt = 0; qt < 2; qt++)
#pragma unroll
        for (int kc = 0; kc < 2; kc++)
            pa[qt][kc] = *(const bf16x8*)(Pr + (qt * 16 + col) * kPSTR + kc * 32 + quad * 8);
#pragma unroll
    for (int n = 0; n < 4; n++) {
        const int row = n * 16 + col;                // dh row of V^T tile
#pragma unroll
        for (int kc = 0; kc < 2; kc++) {
            const bf16x8 vf = *(const bf16x8*)lds_at(vsm, row, kc * 64 + quad * 16);
            __builtin_amdgcn_s_setprio(1);
#pragma unroll
            for (int qt = 0; qt < 2; qt++)
                Oacc[qt][n] = __builtin_amdgcn_mfma_f32_16x16x32_bf16(
                    pa[qt][kc], vf, Oacc[qt][n], 0, 0, 0);
            __builtin_amdgcn_s_setprio(0);
        }
    }
}

__global__ __launch_bounds__(256, 2) void fattn_kernel(const bf16* __restrict__ q_ws,
                                                       const bf16* __restrict__ k_ws,
                                                       const bf16* __restrict__ vt_ws,
                                                       bf16* __restrict__ ctx) {
    __shared__ bf16 Ksm[2][64 * 64];       // 16 KB double-buffered K tile
    __shared__ bf16 Vsm[2][64 * 64];       // 16 KB double-buffered V^T tile
    __shared__ bf16 Pbuf[4][32 * kPSTR];   // 18 KB per-wave P slices -> 50 KB total

    const int idx = blockIdx.x;         // 0..1151; bh fastest -> idx%8 = bh%8 (XCD)
    const int bh  = idx % 96;
    const int qb  = idx / 96;           // 0..11, 128 Q rows per block
    const int b   = bh / kH;
    const int h   = bh - b * kH;
    const int tid  = threadIdx.x;
    const int w    = tid >> 6;
    const int lane = tid & 63;
    const int col  = lane & 15;         // q index within a 16-row tile
    const int quad = lane >> 4;
    const int q0   = qb * 128 + w * 32; // this wave's 32 Q rows (2 tiles)
    const bool active = (q0 < kS);      // wave-uniform; inactive waves still
                                        // stage + hit every barrier

    const bf16* qbase = q_ws  + (size_t)bh * kSP * kDH;
    const bf16* kbase = k_ws  + (size_t)bh * kSP * kDH;
    const bf16* vbase = vt_ws + (size_t)bh * kDH * kSP;

    bf16x8 qf[2][2] = {};
    if (active) {
#pragma unroll
        for (int qt = 0; qt < 2; qt++) {
            const bf16* qr = qbase + (size_t)(q0 + qt * 16 + col) * kDH + quad * 8;
            qf[qt][0] = *(const bf16x8*)(qr);
            qf[qt][1] = *(const bf16x8*)(qr + 32);
        }
    }

    float lsum[2] = {0.f, 0.f};
    floatx4 Oacc[2][4];
#pragma unroll
    for (int qt = 0; qt < 2; qt++)
#pragma unroll
        for (int n = 0; n < 4; n++) Oacc[qt][n] = (floatx4){0.f, 0.f, 0.f, 0.f};

    bf16* const P = &Pbuf[w][0];
    floatx4 sc[2][4];

    // prologue: stage chunk 0
    stage_k(kbase, 0, &Ksm[0][0], w, lane);
    stage_v(vbase, 0, &Vsm[0][0], w, lane);
    __syncthreads();

    int buf = 0;
    // chunks 0..22: stage next, compute current, one barrier per chunk
    for (int c = 0; c < 23; ++c) {
        stage_k(kbase, (c + 1) * 64, &Ksm[buf ^ 1][0], w, lane);
        stage_v(vbase, (c + 1) * 64, &Vsm[buf ^ 1][0], w, lane);
        if (active) {
            qk_mfma_lds(&Ksm[buf][0], qf, sc, col, quad);
            exp_store<false>(sc, P, lsum, c * 64, col, quad);
            pv_lds(&Vsm[buf][0], P, Oacc, col, quad);
        }
        __syncthreads();
        buf ^= 1;
    }
    // chunk 23 (keys 1472..1535; >=1500 masked to exact-zero P)
    if (active) {
        qk_mfma_lds(&Ksm[buf][0], qf, sc, col, quad);
        exp_store<true>(sc, P, lsum, 1472, col, quad);
        pv_lds(&Vsm[buf][0], P, Oacc, col, quad);

#pragma unroll
        for (int qt = 0; qt < 2; qt++) {
            float l = lsum[qt];
            l += __shfl_xor(l, 16);
            l += __shfl_xor(l, 32);
            const float rinv_col = 1.0f / l;         // for q = col of this tile
            float ri[4];
#pragma unroll
            for (int r = 0; r < 4; r++)
                ri[r] = __shfl(rinv_col, quad * 4 + r, 16);
#pragma unroll
            for (int n = 0; n < 4; n++)
#pragma unroll
                for (int r = 0; r < 4; r++) {
                    const int q = q0 + qt * 16 + quad * 4 + r;
                    if (q < kS)
                        ctx[((size_t)(b * kS + q)) * kD + h * kDH + n * 16 + col] =
                            (bf16)(Oacc[qt][n][r] * ri[r]);
                }
        }
    }
}

// ---------------------------------------------------------------------------
extern "C" void kernel_launch(void* const* d_in, const int* in_sizes, int n_in,
                              void* d_out, int out_size, void* d_ws, size_t ws_size,
                              hipStream_t stream) {
    float* out_f = (float*)d_out;   // reference output dtype is float32

    constexpr size_t nX = (size_t)kM * kD;
    constexpr size_t nW = (size_t)kD * kD;
    constexpr size_t per_qkv = (size_t)kB * kH * kSP * kDH;

    bf16* xb    = (bf16*)d_ws;
    bf16* Wqb   = xb + nX;
    bf16* Wkb   = Wqb + nW;
    bf16* Wvb   = Wkb + nW;
    bf16* Wob   = Wvb + nW;
    bf16* q_ws  = Wob + nW;
    bf16* k_ws  = q_ws + per_qkv;
    bf16* vt_ws = k_ws + per_qkv;
    float* bqf  = (float*)(vt_ws + per_qkv);
    float* bvf  = bqf + kD;
    float* bof  = bvf + kD;
    int*  flag  = (int*)(bof + kD);
    bf16* ctx   = xb;   // alias: xb last read by qkv_kernel, ctx written after

    // 1) dtype probe + input normalization to bf16 (biases to f32)
    detect_kernel<<<1, 256, 0, stream>>>(d_in[0], flag);
    cvt_bf16_kernel<<<(int)((nX + 255) / 256), 256, 0, stream>>>(d_in[0], xb,  (int)nX, flag);
    cvt_bf16_kernel<<<(int)((nW + 255) / 256), 256, 0, stream>>>(d_in[1], Wqb, (int)nW, flag);
    cvt_bf16_kernel<<<(int)((nW + 255) / 256), 256, 0, stream>>>(d_in[3], Wkb, (int)nW, flag);
    cvt_bf16_kernel<<<(int)((nW + 255) / 256), 256, 0, stream>>>(d_in[4], Wvb, (int)nW, flag);
    cvt_bf16_kernel<<<(int)((nW + 255) / 256), 256, 0, stream>>>(d_in[6], Wob, (int)nW, flag);
    cvt_f32_kernel<<<3, 256, 0, stream>>>(d_in[2], bqf, kD, flag);
    cvt_f32_kernel<<<3, 256, 0, stream>>>(d_in[5], bvf, kD, flag);
    cvt_f32_kernel<<<3, 256, 0, stream>>>(d_in[7], bof, kD, flag);

    // 2) fused QKV projection (+ padding): 1D grid 1696, XCD-pinned remap
    zeropad_kernel<<<96, 256, 0, stream>>>(q_ws, k_ws, vt_ws);
    qkv_kernel<<<dim3(1696), 256, 0, stream>>>(xb, Wqb, Wkb, Wvb, bqf, bvf,
                                               q_ws, k_ws, vt_ws);

    // 3) flash attention (1D grid: 12 q-blocks x 96 bh, bh fastest for XCD pin)
    fattn_kernel<<<dim3(12 * 96), 256, 0, stream>>>(q_ws, k_ws, vt_ws, ctx);

    // 4) output projection -> float32 d_out
    dim3 ogrid((kM + 127) / 128, kD / 128);   // 94 x 6
    out_kernel<<<ogrid, 256, 0, stream>>>(ctx, Wob, bof, out_f);
}

// Round 13
// 328.694 us; speedup vs baseline: 1.0840x; 1.0316x over previous
//
#include <hip/hip_runtime.h>
#include <hip/hip_bf16.h>

// Problem constants
constexpr int kD  = 768;
constexpr int kH  = 12;
constexpr int kDH = 64;
constexpr int kS  = 1500;
constexpr int kSP = 1504;        // S padded to multiple of 32 (47*32)
constexpr int kB  = 8;
constexpr int kM  = kB * kS;     // 12000 rows for the projections
constexpr float kScale = 0.125f;
// Q pre-scaled by 0.125*log2(e): QK scores become s*log2(e), so softmax's
// e^s == 2^score -> fattn uses a bare v_exp_f32 (no per-element v_mul).
constexpr float kScaleL2 = 0.125f * 1.44269504088896f;
constexpr int kPSTR = 72;        // P row stride (elems): 144B -> b64/b128 aligned
constexpr int kNK = kD / 32;     // 24 K-steps in the projections

typedef __bf16 bf16;
typedef __bf16 bf16x4 __attribute__((ext_vector_type(4)));
typedef __bf16 bf16x8 __attribute__((ext_vector_type(8)));
typedef float  floatx4 __attribute__((ext_vector_type(4)));

// ---------------------------------------------------------------------------
// Dtype probe (round-1 NaN proved inputs are f32; cheap guard retained).
// ---------------------------------------------------------------------------
__global__ __launch_bounds__(256) void detect_kernel(const void* __restrict__ xraw,
                                                     int* __restrict__ flag) {
    __shared__ int bad;
    if (threadIdx.x == 0) bad = 0;
    __syncthreads();
    const bf16* xb = (const bf16*)xraw;
    int c = 0;
    for (int k = 0; k < 16; k++) {
        int idx = 2 * (threadIdx.x + 256 * k);
        float v = fabsf((float)xb[idx]);
        if (!(v == 0.0f || (v > 1e-20f && v < 1e6f))) c++;
    }
    atomicAdd(&bad, c);
    __syncthreads();
    if (threadIdx.x == 0) *flag = (bad > 8) ? 1 : 0;
}

__global__ __launch_bounds__(256) void cvt_bf16_kernel(const void* __restrict__ src,
                                                       bf16* __restrict__ dst, int n,
                                                       const int* __restrict__ flag) {
    int i = blockIdx.x * 256 + threadIdx.x;
    if (i < n) {
        if (*flag)
            dst[i] = (bf16)((const float*)src)[i];
        else
            dst[i] = ((const bf16*)src)[i];
    }
}

// Batched weight conversion: blockIdx.y selects {Wq,Wk,Wv,Wo}; dests are
// contiguous at dst + y*n (layout order matches). 4 launches -> 1.
__global__ __launch_bounds__(256) void cvt_w_kernel(const void* __restrict__ s0,
                                                    const void* __restrict__ s1,
                                                    const void* __restrict__ s2,
                                                    const void* __restrict__ s3,
                                                    bf16* __restrict__ dst, int n,
                                                    const int* __restrict__ flag) {
    const int y = blockIdx.y;
    const void* src = (y == 0) ? s0 : (y == 1) ? s1 : (y == 2) ? s2 : s3;
    bf16* d = dst + (size_t)y * n;
    int i = blockIdx.x * 256 + threadIdx.x;
    if (i < n) {
        if (*flag)
            d[i] = (bf16)((const float*)src)[i];
        else
            d[i] = ((const bf16*)src)[i];
    }
}

// Batched bias conversion: blockIdx.y selects {bq,bv,bo}; dests contiguous.
__global__ __launch_bounds__(256) void cvt_b_kernel(const void* __restrict__ s0,
                                                    const void* __restrict__ s1,
                                                    const void* __restrict__ s2,
                                                    float* __restrict__ dst, int n,
                                                    const int* __restrict__ flag) {
    const int y = blockIdx.y;
    const void* src = (y == 0) ? s0 : (y == 1) ? s1 : s2;
    float* d = dst + (size_t)y * n;
    int i = blockIdx.x * 256 + threadIdx.x;
    if (i < n) {
        if (*flag)
            d[i] = ((const float*)src)[i];
        else
            d[i] = (float)((const bf16*)src)[i];
    }
}

// ---------------------------------------------------------------------------
// Zero the S-padding rows of q/k and padding cols of v^T.
// ---------------------------------------------------------------------------
__global__ __launch_bounds__(256) void zeropad_kernel(bf16* __restrict__ q_ws,
                                                      bf16* __restrict__ k_ws,
                                                      bf16* __restrict__ vt_ws) {
    int t = blockIdx.x * 256 + threadIdx.x;          // 96 bh * 4 s * 64 dh = 24576
    if (t < kB * kH * (kSP - kS) * kDH) {
        int bh  = t >> 8;
        int rem = t & 255;
        int s   = kS + (rem >> 6);
        int dh  = rem & 63;
        size_t qi = ((size_t)bh * kSP + s) * kDH + dh;
        q_ws[qi] = (bf16)0.f;
        k_ws[qi] = (bf16)0.f;
        size_t vi = ((size_t)bh * kDH + dh) * kSP + s;
        vt_ws[vi] = (bf16)0.f;
    }
}

// ---------------------------------------------------------------------------
// GEMM core v4 (R12 measured-good): 128x128 tile, BK=32, 4 waves, 4x4 acc.
// QUAD-BUFFERED, 3-DEEP PREFETCH, vmcnt(8) steady state.
// Ledger: outstanding at wait = {k+1,k+2,k+3} = 12 loads; vmcnt(8) drains
// exactly k+1 (issued two iterations ago); tail k=21/22 -> vmcnt(4)/vmcnt(0).
// ---------------------------------------------------------------------------
__device__ __forceinline__ void async_copy16(const bf16* g, bf16* l) {
    __builtin_amdgcn_global_load_lds(
        (const __attribute__((address_space(1))) void*)g,
        (__attribute__((address_space(3))) void*)l,
        16, 0, 0);
}

#define G_STAGE(KK, SB)                                                         \
    {                                                                           \
        const int k0_ = (KK) * 32;                                              \
        async_copy16(gA + k0_, Asm + (SB) * 4096 + wof);                        \
        async_copy16(gA + (size_t)64 * kD + k0_, Asm + (SB) * 4096 + wof + 2048); \
        async_copy16(gB + k0_, Bsm + (SB) * 4096 + wof);                        \
        async_copy16(gB + (size_t)64 * kD + k0_, Bsm + (SB) * 4096 + wof + 2048); \
    }

#define G_COMPUTE(CB)                                                           \
    {                                                                           \
        const bf16* A_ = Asm + (CB) * 4096;                                     \
        const bf16* B_ = Bsm + (CB) * 4096;                                     \
        bf16x8 af[4], bfr[4];                                                   \
        _Pragma("unroll") for (int i = 0; i < 4; i++)                           \
            af[i] = *(const bf16x8*)(A_ + ((wm + i * 16 + lrow) << 5) + (lq << 3)); \
        _Pragma("unroll") for (int j = 0; j < 4; j++)                           \
            bfr[j] = *(const bf16x8*)(B_ + ((wn + j * 16 + lrow) << 5) + (lq << 3)); \
        _Pragma("unroll") for (int i = 0; i < 4; i++)                           \
            _Pragma("unroll") for (int j = 0; j < 4; j++)                       \
                acc[i][j] = __builtin_amdgcn_mfma_f32_16x16x32_bf16(            \
                    af[i], bfr[j], acc[i][j], 0, 0, 0);                         \
    }

#define G_STEP(KK, CB, SB)                                                      \
    {                                                                           \
        if ((KK) + 3 < kNK) G_STAGE((KK) + 3, SB);                              \
        G_COMPUTE(CB);                                                          \
        if ((KK) + 1 < kNK) {                                                   \
            if ((KK) + 3 < kNK) {                                               \
                asm volatile("s_waitcnt vmcnt(8)" ::: "memory");                \
            } else if ((KK) + 2 < kNK) {                                        \
                asm volatile("s_waitcnt vmcnt(4)" ::: "memory");                \
            } else {                                                            \
                asm volatile("s_waitcnt vmcnt(0)" ::: "memory");                \
            }                                                                   \
            __builtin_amdgcn_s_barrier();                                       \
            __builtin_amdgcn_sched_barrier(0);                                  \
        }                                                                       \
    }

__device__ __forceinline__ void gemm128_qb(const bf16* __restrict__ X,
                                           const bf16* __restrict__ W,
                                           int m0, int n0,
                                           bf16* Asm, bf16* Bsm,   // [4][4096] each
                                           floatx4 acc[4][4]) {
    const int tid  = threadIdx.x;
    const int lane = tid & 63;
    const int w    = tid >> 6;
    const int srow = (w << 4) + (lane >> 2);
    const int scol = (lane & 3) << 3;
    const int lrow = lane & 15;
    const int lq   = lane >> 4;
    const int wm   = (w >> 1) << 6;
    const int wn   = (w & 1) << 6;

    const bf16* gA = X + (size_t)(m0 + srow) * kD + scol;
    const bf16* gB = W + (size_t)(n0 + srow) * kD + scol;
    const int wof = w << 9;      // wave-uniform LDS base; HW adds lane*16B

    // prologue: stage K-steps 0,1,2 into buffers 0,1,2; drain only step 0
    G_STAGE(0, 0);
    G_STAGE(1, 1);
    G_STAGE(2, 2);
    asm volatile("s_waitcnt vmcnt(8)" ::: "memory");
    __builtin_amdgcn_s_barrier();
    __builtin_amdgcn_sched_barrier(0);

#pragma unroll
    for (int ks = 0; ks < kNK; ks += 4) {
        G_STEP(ks,     0, 3);
        G_STEP(ks + 1, 1, 0);
        G_STEP(ks + 2, 2, 1);
        G_STEP(ks + 3, 3, 2);
    }
}

// Fused QKV projection. 1D grid 1696, XCD-pinned remap.
// mat2 (V^T): packed bf16x4 stores (R12 measured-good, alignment proven).
// mat0 NEW: scale by kScaleL2 (0.125*log2e) -> fattn softmax via exp2.
__global__ __launch_bounds__(256) void qkv_kernel(const bf16* __restrict__ X,
                                                  const bf16* __restrict__ Wq,
                                                  const bf16* __restrict__ Wk,
                                                  const bf16* __restrict__ Wv,
                                                  const float* __restrict__ bq,
                                                  const float* __restrict__ bv,
                                                  bf16* __restrict__ q_ws,
                                                  bf16* __restrict__ k_ws,
                                                  bf16* __restrict__ vt_ws) {
    __shared__ bf16 Asm[4 * 4096];
    __shared__ bf16 Bsm[4 * 4096];

    const int lin = blockIdx.x;
    const int wk  = (lin & 7) * 212 + (lin >> 3);
    if (wk >= 94 * 18) return;
    const int bx  = wk / 18;
    const int r   = wk - bx * 18;
    const int m0  = bx << 7;
    const int mat = r / 6;
    const int n0  = (r % 6) << 7;
    const bf16* W = (mat == 0) ? Wq : (mat == 1) ? Wk : Wv;

    floatx4 acc[4][4] = {};
    gemm128_qb(X, W, m0, n0, Asm, Bsm, acc);

    const int tid  = threadIdx.x;
    const int lane = tid & 63;
    const int w    = tid >> 6;
    const int lrow = lane & 15;
    const int lq   = lane >> 4;
    const int wm   = (w >> 1) << 6;
    const int wn   = (w & 1) << 6;

    if (mat == 2) {
#pragma unroll
        for (int i = 0; i < 4; i++) {
#pragma unroll
            for (int j = 0; j < 4; j++) {
                const int n  = n0 + wn + j * 16 + lrow;
                const int hh = n >> 6, dh = n & 63;
                const float bval = bv[n];
                const int m = m0 + wm + i * 16 + lq * 4;
                if (m >= kM) continue;               // m ≡ 0 mod 4 -> m+3 < kM
                const int bb = m / kS, s = m - bb * kS;
                bf16x4 pv;
#pragma unroll
                for (int r2 = 0; r2 < 4; r2++) pv[r2] = (bf16)(acc[i][j][r2] + bval);
                *(bf16x4*)(vt_ws + (((size_t)(bb * kH + hh)) * kDH + dh) * kSP + s) = pv;
            }
        }
    } else {
        bf16* const dst = (mat == 0) ? q_ws : k_ws;
#pragma unroll
        for (int i = 0; i < 4; i++) {
#pragma unroll
            for (int j = 0; j < 4; j++) {
                const int n  = n0 + wn + j * 16 + lrow;
                const int hh = n >> 6, dh = n & 63;
                const float bval = (mat == 0) ? bq[n] : 0.f;
#pragma unroll
                for (int r2 = 0; r2 < 4; r2++) {
                    const int m = m0 + wm + i * 16 + lq * 4 + r2;
                    if (m >= kM) continue;
                    float v = acc[i][j][r2];
                    if (mat == 0) v = (v + bval) * kScaleL2;
                    const int bb = m / kS, s = m - bb * kS;
                    dst[(((size_t)(bb * kH + hh)) * kSP + s) * kDH + dh] = (bf16)v;
                }
            }
        }
    }
}

// Output projection, NEW: 1D grid 568 with bijective XCD-pinned remap
// (564 work blocks = 8 XCDs x {71,71,71,71,70,70,70,70}; m204 formula).
// Same mechanism that halved qkv's FETCH: ctx/Wo panels L2-resident per XCD.
__global__ __launch_bounds__(256) void out_kernel(const bf16* __restrict__ X,
                                                  const bf16* __restrict__ Wo,
                                                  const float* __restrict__ bo,
                                                  float* __restrict__ outf) {
    __shared__ bf16 Asm[4 * 4096];
    __shared__ bf16 Bsm[4 * 4096];

    const int lin = blockIdx.x;          // 0..567
    const int xcd = lin & 7;
    const int ii  = lin >> 3;            // 0..70
    constexpr int q = 564 / 8, r = 564 % 8;   // 70, 4
    if (xcd >= r && ii >= q) return;     // 4 dummy blocks, pre-barrier exit
    const int wk = (xcd < r) ? xcd * (q + 1) + ii
                             : r * (q + 1) + (xcd - r) * q + ii;   // 0..563
    const int bx = wk / 6;
    const int m0 = bx << 7;
    const int n0 = (wk - bx * 6) << 7;

    floatx4 acc[4][4] = {};
    gemm128_qb(X, Wo, m0, n0, Asm, Bsm, acc);

    const int tid  = threadIdx.x;
    const int lane = tid & 63;
    const int w    = tid >> 6;
    const int lrow = lane & 15;
    const int lq   = lane >> 4;
    const int wm   = (w >> 1) << 6;
    const int wn   = (w & 1) << 6;

#pragma unroll
    for (int i = 0; i < 4; i++) {
#pragma unroll
        for (int j = 0; j < 4; j++) {
            const int n = n0 + wn + j * 16 + lrow;
            const float bval = bo[n];
#pragma unroll
            for (int r2 = 0; r2 < 4; r2++) {
                const int m = m0 + wm + i * 16 + lq * 4 + r2;
                if (m >= kM) continue;
                outf[(size_t)m * kD + n] = acc[i][j][r2] + bval;
            }
        }
    }
}

// ---------------------------------------------------------------------------
// Flash attention v8: identical structure to v7 (K/V staged in LDS via
// global_load_lds, double-buffered, XOR bank swizzle), except the softmax
// exp is now a bare v_exp_f32 (2^score; Q pre-scaled by log2e in qkv).
// Removes 32 v_mul per chunk from the exp chain (~half the per-chunk VALU).
// ---------------------------------------------------------------------------
__device__ __forceinline__ const bf16* lds_at(const bf16* sm, int row, int cb) {
    // row-major [64][128B] tile with XOR bank swizzle on the byte column
    return sm + row * 64 + ((cb ^ ((row & 7) << 4)) >> 1);
}

__device__ __forceinline__ void stage_k(const bf16* __restrict__ kbase, int s0,
                                        bf16* ksm, int w, int lane) {
#pragma unroll
    for (int i = 0; i < 2; i++) {
        const int sidx = i * 4 + w;
        const int row  = sidx * 8 + (lane >> 3);
        const int cb   = (lane & 7) << 4;
        const int scb  = cb ^ ((row & 7) << 4);
        int gr = s0 + row;
        if (gr >= kSP) gr = 1472;                    // tail clamp (finite data)
        async_copy16(kbase + (size_t)gr * kDH + (scb >> 1), ksm + sidx * 512);
    }
}

__device__ __forceinline__ void stage_v(const bf16* __restrict__ vbase, int s0,
                                        bf16* vsm, int w, int lane) {
#pragma unroll
    for (int i = 0; i < 2; i++) {
        const int sidx = i * 4 + w;
        const int row  = sidx * 8 + (lane >> 3);     // dh
        const int cb   = (lane & 7) << 4;
        const int scb  = cb ^ ((row & 7) << 4);
        int key = s0 + (scb >> 1);
        if (key >= kSP) key = 1472;                  // tail clamp (finite data)
        async_copy16(vbase + (size_t)row * kSP + key, vsm + sidx * 512);
    }
}

__device__ __forceinline__ void qk_mfma_lds(const bf16* ksm,
                                            const bf16x8 qf[2][2],
                                            floatx4 sc[2][4],
                                            int col, int quad) {
#pragma unroll
    for (int t = 0; t < 4; t++) {
        const int r = 16 * t + col;
        const bf16x8 kf0 = *(const bf16x8*)lds_at(ksm, r, quad * 16);
        const bf16x8 kf1 = *(const bf16x8*)lds_at(ksm, r, 64 + quad * 16);
        __builtin_amdgcn_s_setprio(1);
#pragma unroll
        for (int qt = 0; qt < 2; qt++) {
            floatx4 a = {0.f, 0.f, 0.f, 0.f};
            a = __builtin_amdgcn_mfma_f32_16x16x32_bf16(kf0, qf[qt][0], a, 0, 0, 0);
            a = __builtin_amdgcn_mfma_f32_16x16x32_bf16(kf1, qf[qt][1], a, 0, 0, 0);
            sc[qt][t] = a;
        }
        __builtin_amdgcn_s_setprio(0);
    }
}

template <bool MASK>
__device__ __forceinline__ void exp_store(const floatx4 sc[2][4],
                                          bf16* __restrict__ Pw,
                                          float lsum[2],
                                          int s0, int col, int quad) {
#pragma unroll
    for (int qt = 0; qt < 2; qt++)
#pragma unroll
        for (int t = 0; t < 4; t++) {
            bf16x4 pv;
#pragma unroll
            for (int r = 0; r < 4; r++) {
                float p;
                if (MASK && (s0 + 16 * t + quad * 4 + r >= kS)) {
                    p = 0.f;
                } else {
                    // scores are s*log2e -> 2^score == e^s (exact fold)
                    asm("v_exp_f32 %0, %1" : "=v"(p) : "v"(sc[qt][t][r]));
                }
                lsum[qt] += p;
                pv[r] = (bf16)p;
            }
            *(bf16x4*)(Pw + (qt * 16 + col) * kPSTR + 16 * t + quad * 4) = pv;
        }
}

__device__ __forceinline__ void pv_lds(const bf16* vsm,
                                       const bf16* __restrict__ Pr,
                                       floatx4 Oacc[2][4],
                                       int col, int quad) {
    bf16x8 pa[2][2];
#pragma unroll
    for (int qt = 0; qt < 2; qt++)
#pragma unroll
        for (int kc = 0; kc < 2; kc++)
            pa[qt][kc] = *(const bf16x8*)(Pr + (qt * 16 + col) * kPSTR + kc * 32 + quad * 8);
#pragma unroll
    for (int n = 0; n < 4; n++) {
        const int row = n * 16 + col;                // dh row of V^T tile
#pragma unroll
        for (int kc = 0; kc < 2; kc++) {
            const bf16x8 vf = *(const bf16x8*)lds_at(vsm, row, kc * 64 + quad * 16);
            __builtin_amdgcn_s_setprio(1);
#pragma unroll
            for (int qt = 0; qt < 2; qt++)
                Oacc[qt][n] = __builtin_amdgcn_mfma_f32_16x16x32_bf16(
                    pa[qt][kc], vf, Oacc[qt][n], 0, 0, 0);
            __builtin_amdgcn_s_setprio(0);
        }
    }
}

__global__ __launch_bounds__(256, 2) void fattn_kernel(const bf16* __restrict__ q_ws,
                                                       const bf16* __restrict__ k_ws,
                                                       const bf16* __restrict__ vt_ws,
                                                       bf16* __restrict__ ctx) {
    __shared__ bf16 Ksm[2][64 * 64];       // 16 KB double-buffered K tile
    __shared__ bf16 Vsm[2][64 * 64];       // 16 KB double-buffered V^T tile
    __shared__ bf16 Pbuf[4][32 * kPSTR];   // 18 KB per-wave P slices -> 50 KB total

    const int idx = blockIdx.x;         // 0..1151; bh fastest -> idx%8 = bh%8 (XCD)
    const int bh  = idx % 96;
    const int qb  = idx / 96;           // 0..11, 128 Q rows per block
    const int b   = bh / kH;
    const int h   = bh - b * kH;
    const int tid  = threadIdx.x;
    const int w    = tid >> 6;
    const int lane = tid & 63;
    const int col  = lane & 15;         // q index within a 16-row tile
    const int quad = lane >> 4;
    const int q0   = qb * 128 + w * 32; // this wave's 32 Q rows (2 tiles)
    const bool active = (q0 < kS);      // wave-uniform; inactive waves still
                                        // stage + hit every barrier

    const bf16* qbase = q_ws  + (size_t)bh * kSP * kDH;
    const bf16* kbase = k_ws  + (size_t)bh * kSP * kDH;
    const bf16* vbase = vt_ws + (size_t)bh * kDH * kSP;

    bf16x8 qf[2][2] = {};
    if (active) {
#pragma unroll
        for (int qt = 0; qt < 2; qt++) {
            const bf16* qr = qbase + (size_t)(q0 + qt * 16 + col) * kDH + quad * 8;
            qf[qt][0] = *(const bf16x8*)(qr);
            qf[qt][1] = *(const bf16x8*)(qr + 32);
        }
    }

    float lsum[2] = {0.f, 0.f};
    floatx4 Oacc[2][4];
#pragma unroll
    for (int qt = 0; qt < 2; qt++)
#pragma unroll
        for (int n = 0; n < 4; n++) Oacc[qt][n] = (floatx4){0.f, 0.f, 0.f, 0.f};

    bf16* const P = &Pbuf[w][0];
    floatx4 sc[2][4];

    // prologue: stage chunk 0
    stage_k(kbase, 0, &Ksm[0][0], w, lane);
    stage_v(vbase, 0, &Vsm[0][0], w, lane);
    __syncthreads();

    int buf = 0;
    // chunks 0..22: stage next, compute current, one barrier per chunk
    for (int c = 0; c < 23; ++c) {
        stage_k(kbase, (c + 1) * 64, &Ksm[buf ^ 1][0], w, lane);
        stage_v(vbase, (c + 1) * 64, &Vsm[buf ^ 1][0], w, lane);
        if (active) {
            qk_mfma_lds(&Ksm[buf][0], qf, sc, col, quad);
            exp_store<false>(sc, P, lsum, c * 64, col, quad);
            pv_lds(&Vsm[buf][0], P, Oacc, col, quad);
        }
        __syncthreads();
        buf ^= 1;
    }
    // chunk 23 (keys 1472..1535; >=1500 masked to exact-zero P)
    if (active) {
        qk_mfma_lds(&Ksm[buf][0], qf, sc, col, quad);
        exp_store<true>(sc, P, lsum, 1472, col, quad);
        pv_lds(&Vsm[buf][0], P, Oacc, col, quad);

#pragma unroll
        for (int qt = 0; qt < 2; qt++) {
            float l = lsum[qt];
            l += __shfl_xor(l, 16);
            l += __shfl_xor(l, 32);
            const float rinv_col = 1.0f / l;         // for q = col of this tile
            float ri[4];
#pragma unroll
            for (int r = 0; r < 4; r++)
                ri[r] = __shfl(rinv_col, quad * 4 + r, 16);
#pragma unroll
            for (int n = 0; n < 4; n++)
#pragma unroll
                for (int r = 0; r < 4; r++) {
                    const int q = q0 + qt * 16 + quad * 4 + r;
                    if (q < kS)
                        ctx[((size_t)(b * kS + q)) * kD + h * kDH + n * 16 + col] =
                            (bf16)(Oacc[qt][n][r] * ri[r]);
                }
        }
    }
}

// ---------------------------------------------------------------------------
extern "C" void kernel_launch(void* const* d_in, const int* in_sizes, int n_in,
                              void* d_out, int out_size, void* d_ws, size_t ws_size,
                              hipStream_t stream) {
    float* out_f = (float*)d_out;   // reference output dtype is float32

    constexpr size_t nX = (size_t)kM * kD;
    constexpr size_t nW = (size_t)kD * kD;
    constexpr size_t per_qkv = (size_t)kB * kH * kSP * kDH;

    bf16* xb    = (bf16*)d_ws;
    bf16* Wqb   = xb + nX;
    bf16* Wkb   = Wqb + nW;
    bf16* Wvb   = Wkb + nW;
    bf16* Wob   = Wvb + nW;
    bf16* q_ws  = Wob + nW;
    bf16* k_ws  = q_ws + per_qkv;
    bf16* vt_ws = k_ws + per_qkv;
    float* bqf  = (float*)(vt_ws + per_qkv);
    float* bvf  = bqf + kD;
    float* bof  = bvf + kD;
    int*  flag  = (int*)(bof + kD);
    bf16* ctx   = xb;   // alias: xb last read by qkv_kernel, ctx written after

    // 1) dtype probe + input normalization (batched: 12 -> 8 launches)
    detect_kernel<<<1, 256, 0, stream>>>(d_in[0], flag);
    cvt_bf16_kernel<<<(int)((nX + 255) / 256), 256, 0, stream>>>(d_in[0], xb, (int)nX, flag);
    cvt_w_kernel<<<dim3((int)((nW + 255) / 256), 4), 256, 0, stream>>>(
        d_in[1], d_in[3], d_in[4], d_in[6], Wqb, (int)nW, flag);
    cvt_b_kernel<<<dim3(3, 3), 256, 0, stream>>>(
        d_in[2], d_in[5], d_in[7], bqf, kD, flag);

    // 2) fused QKV projection (+ padding): 1D grid 1696, XCD-pinned remap
    zeropad_kernel<<<96, 256, 0, stream>>>(q_ws, k_ws, vt_ws);
    qkv_kernel<<<dim3(1696), 256, 0, stream>>>(xb, Wqb, Wkb, Wvb, bqf, bvf,
                                               q_ws, k_ws, vt_ws);

    // 3) flash attention (1D grid: 12 q-blocks x 96 bh, bh fastest for XCD pin)
    fattn_kernel<<<dim3(12 * 96), 256, 0, stream>>>(q_ws, k_ws, vt_ws, ctx);

    // 4) output projection -> float32 d_out (1D grid 568, XCD remap)
    out_kernel<<<dim3(568), 256, 0, stream>>>(ctx, Wob, bof, out_f);
}